// Round 8
// baseline (1657.992 us; speedup 1.0000x reference)
//
#include <hip/hip_runtime.h>
#include <hip/hip_bf16.h>
#include <stdint.h>

// B=1024, D_in=1024, D_hid=1024, D_out=512, D_future=32
// Outputs: Act [1024*512], Act_bar [32*1024*512], hx2 [1024*1024], cx2 [1024*1024]
//
// Algebraic restructure: r_t = hd_t@Wrp2^T + br2  (Wrp2 = Wrr@Wrp), so
//   gates_t = hd_{t-1} @ (W_ih@Wrp2 + W_hh)^T + (biasD + W_ih@br2)   [t>=1]
//   gates_0 = hd0 @ W_hh^T + biasD                                    [r0 = 0]
//
// R6: row-partitioned decoder, per-group flag sync (no global barrier).
// R7: hd published via relaxed agent atomics (no wbl2); 739us, 23us/step:
// MfmaUtil 15% x 23us = 3.5us = exact MFMA floor -> 20us/step is handoff.
// R8: (a) u64 packed atomics (4 bf16/store, 8x fewer coherence transactions
// than R7's per-lane u32); (b) 512 blocks x 512 thr = 2 blocks/CU (16
// waves/CU) -> co-resident blocks at different phases overlap; (c) per-
// producer span polling: span j needs only producers 2j,2j+1; consumer
// starts at its OWN span (ready right after its publish) and rotates ->
// flag waits fold into the double-buffered K-loop. 128B cache lines align
// exactly with 64-unit producer boundaries (no partial-line staleness).

typedef unsigned short ushort_t;
typedef unsigned long long u64_t;
typedef __attribute__((ext_vector_type(8))) short short8;   // 8 x bf16
typedef __attribute__((ext_vector_type(4))) float floatx4;  // 4 x fp32 acc

__device__ __forceinline__ unsigned short f2bf(float f) {
    unsigned int u = __float_as_uint(f);
    u += 0x7FFF + ((u >> 16) & 1);   // RNE
    return (unsigned short)(u >> 16);
}
__device__ __forceinline__ float bf2f(unsigned short u) {
    return __uint_as_float(((unsigned int)u) << 16);
}
__device__ __forceinline__ float sigm(float x) { return 1.f / (1.f + __expf(-x)); }

__device__ __forceinline__ void glds16(const ushort_t* g, const ushort_t* l) {
    __builtin_amdgcn_global_load_lds(
        (const __attribute__((address_space(1))) uint32_t*)g,
        (__attribute__((address_space(3))) uint32_t*)l, 16, 0, 0);
}

__device__ __forceinline__ unsigned ld_rlx(const unsigned* p) {
    return __hip_atomic_load(p, __ATOMIC_RELAXED, __HIP_MEMORY_SCOPE_AGENT);
}
__device__ __forceinline__ void st_rlx(unsigned* p, unsigned v) {
    __hip_atomic_store(p, v, __ATOMIC_RELAXED, __HIP_MEMORY_SCOPE_AGENT);
}
__device__ __forceinline__ void st_rlx64(u64_t* p, u64_t v) {
    __hip_atomic_store(p, v, __ATOMIC_RELAXED, __HIP_MEMORY_SCOPE_AGENT);
}

// ---------------- generic GEMM (round-2 proven, zero LDS conflicts) ----------
// C[m][n] = sum_k A[m][k]*Bw[n][k] (+bias[n]), optional relu; fp32/bf16 out.
// NT: nontemporal fp32 stores (pure outputs, avoid RFO). Grid (N/128, M/128, kz).
template <bool WF, bool WB, bool RELU, bool NT>
__global__ __launch_bounds__(256)
void gemm_bt(const ushort_t* __restrict__ A, int lda,
             const ushort_t* __restrict__ Bw, int ldb,
             int Kloop, int kzOff,
             const float* __restrict__ bias,
             float* __restrict__ Cf, int ldcf, size_t czStride,
             ushort_t* __restrict__ Cb, int ldcb) {
    __shared__ __align__(16) ushort_t As[128 * 32];
    __shared__ __align__(16) ushort_t Bs[128 * 32];
    const int t = threadIdx.x;
    const int l = t & 63;
    const int w = t >> 6;
    // XCD-aware bijective swizzle: XCD (flat%8) gets a contiguous m-range,
    // iterating n fastest -> A-panel + B-tile stay in the local L2.
    int bx = blockIdx.x, by = blockIdx.y;
    if ((gridDim.y & 7) == 0) {
        const int flat = bx + gridDim.x * by;
        const int xcd = flat & 7;
        const int j = flat >> 3;
        const int jm = j / gridDim.x;       // uniform per-block, cheap
        by = xcd * (gridDim.y >> 3) + jm;
        bx = j - jm * gridDim.x;
    }
    const int m0 = by << 7;
    const int n0 = bx << 7;
    const int kz = blockIdx.z;
    A  += (size_t)kz * kzOff;
    Bw += (size_t)kz * kzOff;
    if (WF) Cf += (size_t)kz * czStride;
    const int wm = (w >> 1) << 6;
    const int wn = (w & 1) << 6;
    const int lr = l & 15;
    const int lg = l >> 4;

    floatx4 acc[4][4] = {};

    const int srow = (w << 4) + (l >> 2);
    const int cc = ((l & 3) - ((l >> 3) & 3)) & 3;
    const int scol = cc << 3;
    const ushort_t* Ag0 = A + (size_t)(m0 + srow) * lda + scol;
    const ushort_t* Ag1 = A + (size_t)(m0 + 64 + srow) * lda + scol;
    const ushort_t* Bg0 = Bw + (size_t)(n0 + srow) * ldb + scol;
    const ushort_t* Bg1 = Bw + (size_t)(n0 + 64 + srow) * ldb + scol;
    const ushort_t* lA0 = &As[t * 8];
    const ushort_t* lA1 = &As[2048 + t * 8];
    const ushort_t* lB0 = &Bs[t * 8];
    const ushort_t* lB1 = &Bs[2048 + t * 8];

    int aoff[4], boff[4];
#pragma unroll
    for (int i = 0; i < 4; i++) {
        const int Ra = wm + i * 16 + lr;
        aoff[i] = ((Ra << 2) + ((lg + ((Ra >> 1) & 3)) & 3)) << 3;
        const int Rb = wn + i * 16 + lr;
        boff[i] = ((Rb << 2) + ((lg + ((Rb >> 1) & 3)) & 3)) << 3;
    }

    for (int kk = 0; kk < Kloop; kk += 32) {
        glds16(Ag0 + kk, lA0);
        glds16(Ag1 + kk, lA1);
        glds16(Bg0 + kk, lB0);
        glds16(Bg1 + kk, lB1);
        __syncthreads();
        short8 af[4], bfr[4];
#pragma unroll
        for (int i = 0; i < 4; i++) af[i] = *(const short8*)&As[aoff[i]];
#pragma unroll
        for (int j = 0; j < 4; j++) bfr[j] = *(const short8*)&Bs[boff[j]];
#pragma unroll
        for (int i = 0; i < 4; i++)
#pragma unroll
            for (int j = 0; j < 4; j++)
                acc[i][j] = __builtin_amdgcn_mfma_f32_16x16x32_bf16(af[i], bfr[j], acc[i][j], 0, 0, 0);
        __syncthreads();
    }

#pragma unroll
    for (int i = 0; i < 4; i++) {
#pragma unroll
        for (int j = 0; j < 4; j++) {
            const int col = n0 + wn + j * 16 + lr;
            const float bv = bias ? bias[col] : 0.f;
#pragma unroll
            for (int r = 0; r < 4; r++) {
                const int row = m0 + wm + i * 16 + lg * 4 + r;
                float v = acc[i][j][r] + bv;
                if (RELU) v = fmaxf(v, 0.f);
                if (WF) {
                    if (NT) __builtin_nontemporal_store(v, &Cf[(size_t)row * ldcf + col]);
                    else Cf[(size_t)row * ldcf + col] = v;
                }
                if (WB) Cb[(size_t)row * ldcb + col] = f2bf(v);
            }
        }
    }
}

// ---------------- fused gates GEMM + LSTM pointwise (single-step) -------------
// Still used for the static LSTM (K=3072). Same structure as before.
template <bool HF, bool NT>
__global__ __launch_bounds__(256, 2)
void gates_fused(const ushort_t* __restrict__ A, int lda,
                 const ushort_t* __restrict__ WI, int K,
                 const float* __restrict__ biasI,
                 const float* __restrict__ cin, float* __restrict__ cout,
                 ushort_t* __restrict__ hbf, int ldh,
                 float* __restrict__ hf) {
    __shared__ __align__(16) float Cs[64 * 132];         // 33.8 KB
    ushort_t* AsBase = (ushort_t*)Cs;                    // 2 bufs x 8192 elems = 32 KB
    const int t = threadIdx.x;
    const int l = t & 63;
    const int w = t >> 6;
    const int flat = blockIdx.x + (blockIdx.y << 5);
    const int xcd = flat & 7;
    const int jsw = flat >> 3;
    const int bn = (xcd << 2) + (jsw >> 4);   // 0..31 n-tile
    const int bm = jsw & 15;                  // 0..15 m-tile
    const int m0 = bm << 6;    // 64-row tile
    const int n0 = bn << 7;    // 128 gate-rows = 32 units
    const int u0 = bn << 5;
    const int lr = l & 15;
    const int lg = l >> 4;

    floatx4 acc[4][2] = {};

    const int srow = t >> 2;
    const int cc = ((t & 3) - ((t >> 3) & 3)) & 3;
    const int scol = cc << 3;
    const ushort_t* Ag = A + (size_t)(m0 + srow) * lda + scol;

    int aoff[4];
#pragma unroll
    for (int i = 0; i < 4; i++) {
        const int Ra = i * 16 + lr;
        aoff[i] = ((Ra << 2) + ((lg + ((Ra >> 1) & 3)) & 3)) << 3;
    }
    const ushort_t* BgW[2];
#pragma unroll
    for (int jf = 0; jf < 2; jf++)
        BgW[jf] = WI + (size_t)(n0 + (w << 5) + jf * 16 + lr) * K + (lg << 3);

    auto issueA = [&](int b, int sp) {
#pragma unroll
        for (int s = 0; s < 4; s++)
            glds16(Ag + sp * 128 + s * 32, AsBase + b * 8192 + s * 2048 + t * 8);
    };
    auto loadB = [&](short8 (&br)[4][2], int sp) {
#pragma unroll
        for (int s = 0; s < 4; s++)
#pragma unroll
            for (int jf = 0; jf < 2; jf++)
                br[s][jf] = *(const short8*)(BgW[jf] + sp * 128 + s * 32);
    };
    auto compute = [&](int b, short8 (&br)[4][2]) {
#pragma unroll
        for (int s = 0; s < 4; s++) {
            short8 af[4];
#pragma unroll
            for (int i = 0; i < 4; i++)
                af[i] = *(const short8*)(AsBase + b * 8192 + s * 2048 + aoff[i]);
#pragma unroll
            for (int i = 0; i < 4; i++)
#pragma unroll
                for (int jf = 0; jf < 2; jf++)
                    acc[i][jf] = __builtin_amdgcn_mfma_f32_16x16x32_bf16(af[i], br[s][jf], acc[i][jf], 0, 0, 0);
        }
    };

    short8 b0[4][2], b1[4][2];
    const int NS = K >> 7;
    issueA(0, 0);
    loadB(b0, 0);
    for (int sp = 0; sp < NS; sp += 2) {
        __syncthreads();
        if (sp + 1 < NS) { issueA(1, sp + 1); loadB(b1, sp + 1); }
        compute(0, b0);
        __syncthreads();
        if (sp + 2 < NS) { issueA(0, sp + 2); loadB(b0, sp + 2); }
        compute(1, b1);
    }
    __syncthreads();

#pragma unroll
    for (int i = 0; i < 4; i++)
#pragma unroll
        for (int jf = 0; jf < 2; jf++) {
            const int colb = (w << 5) + jf * 16 + lr;
#pragma unroll
            for (int r = 0; r < 4; r++)
                Cs[(i * 16 + lg * 4 + r) * 132 + colb] = acc[i][jf][r];
        }
    __syncthreads();

#pragma unroll
    for (int p = 0; p < 8; p++) {
        const int row = p * 8 + (t >> 5);
        const int uu = t & 31;
        const float4 g4 = *(const float4*)&Cs[row * 132 + uu * 4];
        const int grow = m0 + row;
        const int gu = u0 + uu;
        const float4 b4 = *(const float4*)&biasI[gu * 4];
        const float iv = sigm(g4.x + b4.x);
        const float fv = sigm(g4.y + b4.y);
        const float gv = tanhf(g4.z + b4.z);
        const float ov = sigm(g4.w + b4.w);
        const size_t cidx = (size_t)grow * 1024 + gu;
        const float c = fv * cin[cidx] + iv * gv;
        const float h = ov * tanhf(c);
        if (NT) __builtin_nontemporal_store(c, &cout[cidx]);
        else cout[cidx] = c;
        hbf[(size_t)grow * ldh + gu] = f2bf(h);
        if (HF) {
            if (NT) __builtin_nontemporal_store(h, &hf[cidx]);
            else hf[cidx] = h;
        }
    }
}

// ---------------- row-partitioned 32-step decoder (per-span producer sync) ----
// Grid 512 blocks x 512 threads (2 blocks/CU). Block (g = bid>>4 in 0..31,
// q = bid&15): rows [32g,32g+32) x gate-cols [256q,256q+256) (units
// [64q,64q+64)). XCD = bid%8 = q%8 -> 2 W-quarters = 1MB/XCD, L2-resident.
// hd published via packed-u64 relaxed agent atomics (4 bf16/store); span j
// of the K-loop polls only its 2 producers (2j, 2j+1), starting at the
// consumer's own span (ready immediately after its own publish).
__global__ __launch_bounds__(512, 4)
void gates_rows(ushort_t* __restrict__ HD,          // slot base; A(s) = HD + s*SLOT
                const ushort_t* __restrict__ Wh,    // WhhI   (s=0)
                const ushort_t* __restrict__ Wg,    // WgI    (s>=1)
                const float* __restrict__ biasD,
                const float* __restrict__ biasG,
                const float* __restrict__ cx,       // c init
                ushort_t* __restrict__ hbarb,
                unsigned* __restrict__ flags) {     // 512 x 16 u32 (64B apart)
    const size_t SLOT = 1048576;
    __shared__ __align__(16) float Cs[32 * 260];         // 33.3 KB
    ushort_t* AsBase = (ushort_t*)Cs;                    // 2 bufs x 4096 elems = 16 KB
    const int t = threadIdx.x;          // 0..511
    const int l = t & 63;
    const int w = t >> 6;               // 0..7 (wave); gate-cols [w*32,w*32+32)
    const int bid = blockIdx.x;
    const int g = bid >> 4;             // row group 0..31 (32 rows each)
    const int q = bid & 15;             // unit quarter 0..15 (64 units each)
    const int m0 = g << 5;              // 32 rows
    const int n0 = q << 8;              // 256 gate-cols
    const int u0 = q << 6;              // 64 units
    const int lr = l & 15;
    const int lg = l >> 4;
    const int fbase = g << 4;           // flag base for this group

    // A staging: span = 32 rows x 128 k; 4 subtiles of 32r x 32k (1024 elems);
    // thread: sub = t>>7, u7 = t&127; srow = u7>>2; swizzle cc keyed (u7&3,u7>>3)
    // -> same rotation invariant as the proven aoff formula.
    const int u7 = t & 127;
    const int sub = t >> 7;             // 0..3
    const int srow = u7 >> 2;           // 0..31
    const int cc = ((u7 & 3) - ((u7 >> 3) & 3)) & 3;
    const ushort_t* Ag = HD + (size_t)(m0 + srow) * 1024 + (cc << 3);  // slot 0

    int aoff[2];
#pragma unroll
    for (int i = 0; i < 2; i++) {
        const int Ra = i * 16 + lr;
        aoff[i] = ((Ra << 2) + ((lg + ((Ra >> 1) & 3)) & 3)) << 3;
    }

    // pointwise mapping: thread -> 4 adjacent units x 1 row
    const int v = t & 15;               // unit quad 0..15 (units u0+4v..u0+4v+3)
    const int rb = t >> 4;              // row 0..31
    float4 bd[4], bg[4];
#pragma unroll
    for (int k = 0; k < 4; k++) {
        bd[k] = *(const float4*)&biasD[(u0 + 4 * v + k) * 4];
        bg[k] = *(const float4*)&biasG[(u0 + 4 * v + k) * 4];
    }
    float cst[4], hsum[4];
#pragma unroll
    for (int k = 0; k < 4; k++) {
        cst[k] = cx[(size_t)(m0 + rb) * 1024 + u0 + 4 * v + k];
        hsum[k] = 0.f;
    }

    const int j0 = q >> 1;              // own span: ready first
    for (int s = 0; s < 32; ++s) {
        const ushort_t* W = s ? Wg : Wh;
        const ushort_t* BgW[2];
#pragma unroll
        for (int jf = 0; jf < 2; jf++)
            BgW[jf] = W + (size_t)(n0 + (w << 5) + jf * 16 + lr) * 1024 + (lg << 3);

        floatx4 acc[2][2] = {};

        auto pollSpan = [&](int sp) {   // wait for the 2 producers of span J(sp)
            if (s && t < 2) {
                const int jg = (j0 + sp) & 7;
                while (ld_rlx(&flags[(fbase | (2 * jg + t)) << 4]) < (unsigned)s)
                    __builtin_amdgcn_s_sleep(2);
            }
        };
        auto issueA = [&](int b, int sp) {
            const int jg = (j0 + sp) & 7;
            glds16(Ag + jg * 128 + sub * 32,
                   AsBase + b * 4096 + sub * 1024 + u7 * 8);
        };
        auto loadB = [&](short8 (&br)[4][2], int sp) {
            const int jg = (j0 + sp) & 7;
#pragma unroll
            for (int ss = 0; ss < 4; ss++)
#pragma unroll
                for (int jf = 0; jf < 2; jf++)
                    br[ss][jf] = *(const short8*)(BgW[jf] + jg * 128 + ss * 32);
        };
        auto compute = [&](int b, short8 (&br)[4][2]) {
#pragma unroll
            for (int ss = 0; ss < 4; ss++) {
                short8 af[2];
#pragma unroll
                for (int i = 0; i < 2; i++)
                    af[i] = *(const short8*)(AsBase + b * 4096 + ss * 1024 + aoff[i]);
#pragma unroll
                for (int i = 0; i < 2; i++)
#pragma unroll
                    for (int jf = 0; jf < 2; jf++)
                        acc[i][jf] = __builtin_amdgcn_mfma_f32_16x16x32_bf16(af[i], br[ss][jf], acc[i][jf], 0, 0, 0);
            }
        };

        short8 b0[4][2], b1[4][2];
        pollSpan(0);
        __syncthreads();                  // poll(0) done; prev-step Cs reads done
        issueA(0, 0);
        loadB(b0, 0);
        for (int sp = 0; sp < 8; sp += 2) {
            pollSpan(sp + 1);
            __syncthreads();              // drains span sp glds16; poll(sp+1) done
            if (sp + 1 < 8) { issueA(1, sp + 1); loadB(b1, sp + 1); }
            compute(0, b0);
            pollSpan(sp + 2);
            __syncthreads();              // drains span sp+1 glds16; poll(sp+2) done
            if (sp + 2 < 8) { issueA(0, sp + 2); loadB(b0, sp + 2); }
            compute(1, b1);
        }
        __syncthreads();                  // all ds_reads done before Cs overwrite

        // epilogue: acc -> Cs (stride 260, waves have disjoint col ranges)
#pragma unroll
        for (int i = 0; i < 2; i++)
#pragma unroll
            for (int jf = 0; jf < 2; jf++) {
                const int colb = (w << 5) + jf * 16 + lr;
#pragma unroll
                for (int r = 0; r < 4; r++)
                    Cs[(i * 16 + lg * 4 + r) * 260 + colb] = acc[i][jf][r];
            }
        __syncthreads();

        // pointwise: 4 units x 1 row per thread; one packed u64 publish
        ushort_t* Hout = HD + (size_t)(s + 1) * SLOT;
        u64_t pack = 0;
#pragma unroll
        for (int k = 0; k < 4; k++) {
            const float4 g4 = *(const float4*)&Cs[rb * 260 + v * 16 + 4 * k];
            const float4 b4 = s ? bg[k] : bd[k];
            const float iv = sigm(g4.x + b4.x);
            const float fv = sigm(g4.y + b4.y);
            const float gv = tanhf(g4.z + b4.z);
            const float ov = sigm(g4.w + b4.w);
            cst[k] = fv * cst[k] + iv * gv;
            const float h = ov * tanhf(cst[k]);
            pack |= ((u64_t)f2bf(h)) << (16 * k);
            hsum[k] += h;
        }
        u64_t* dst = (u64_t*)&Hout[(size_t)(m0 + rb) * 1024 + u0 + 4 * v];
        if (s < 31) st_rlx64(dst, pack);   // write-through publish
        else *dst = pack;                  // last slot: kernel-end release flushes

        __syncthreads();                  // vmcnt(0): all publishes complete; Cs reads done
        if (s < 31 && t == 0)             // relaxed flag (no wbl2)
            st_rlx(&flags[(fbase | q) << 4], (unsigned)(s + 1));
        Ag += SLOT;                       // next step reads slot s+1
    }

    // hbar = mean over the 32 h's (fp32 accumulation, pre-rounding)
    u64_t hb = 0;
#pragma unroll
    for (int k = 0; k < 4; k++)
        hb |= ((u64_t)f2bf(hsum[k] * (1.f / 32.f))) << (16 * k);
    *(u64_t*)&hbarb[(size_t)(m0 + rb) * 1024 + u0 + 4 * v] = hb;
}

// ---------------- small prep kernels -----------------------------------------
__global__ void zero_bar(unsigned* __restrict__ b, int n) {
    int i = blockIdx.x * 256 + threadIdx.x;
    if (i < n) b[i] = 0u;
}

__global__ void pack2_bf(ushort_t* __restrict__ dst, const float* __restrict__ s1, int K1,
                         const float* __restrict__ s2, int K2) {
    const int n = blockIdx.y;
    const int k = blockIdx.x * 256 + threadIdx.x;
    const int Kt = K1 + K2;
    float v = (k < K1) ? s1[(size_t)n * K1 + k] : s2[(size_t)n * K2 + (k - K1)];
    dst[(size_t)n * Kt + k] = f2bf(v);
}

// dst[c][r] = bf(src[r][c]); grid (R/256, C)
__global__ void tpose_bf(ushort_t* __restrict__ dst, const float* __restrict__ src,
                         int R, int C) {
    const int c = blockIdx.y;
    const int r = blockIdx.x * 256 + threadIdx.x;
    dst[(size_t)c * R + r] = f2bf(src[(size_t)r * C + c]);
}

// WhhI[4u+g][k] = bf(Whh[(g<<10)+u][k]); grid (4, 4096)
__global__ void ileave_whh_k(ushort_t* __restrict__ dst, const float* __restrict__ Whh) {
    const int rI = blockIdx.y;
    const int k = blockIdx.x * 256 + threadIdx.x;
    const int r = ((rI & 3) << 10) + (rI >> 2);
    dst[(size_t)rI * 1024 + k] = f2bf(Whh[(size_t)r * 1024 + k]);
}

// WgI[4u+g][k] = bf(Wgf[r][k] + Whh[r][k]); grid (4, 4096)
__global__ void ileave_add_k(ushort_t* __restrict__ dst, const float* __restrict__ Wgf,
                             const float* __restrict__ Whh) {
    const int rI = blockIdx.y;
    const int k = blockIdx.x * 256 + threadIdx.x;
    const int r = ((rI & 3) << 10) + (rI >> 2);
    dst[(size_t)rI * 1024 + k] = f2bf(Wgf[(size_t)r * 1024 + k] + Whh[(size_t)r * 1024 + k]);
}

// WcatSI[4u+g][k]: k<2048 from Wih_sta[r][k], else Whh_sta[r][k-2048]; grid (12, 4096)
__global__ void ileave_sta_k(ushort_t* __restrict__ dst, const float* __restrict__ Wih,
                             const float* __restrict__ Whh) {
    const int rI = blockIdx.y;
    const int k = blockIdx.x * 256 + threadIdx.x;
    const int r = ((rI & 3) << 10) + (rI >> 2);
    float v = (k < 2048) ? Wih[(size_t)r * 2048 + k] : Whh[(size_t)r * 1024 + (k - 2048)];
    dst[(size_t)rI * 3072 + k] = f2bf(v);
}

// biasI[4u+g] = b_ih[r] + b_hh[r]; grid 16
__global__ void bias_il_k(float* __restrict__ dst, const float* __restrict__ b_ih,
                          const float* __restrict__ b_hh) {
    const int rI = blockIdx.x * 256 + threadIdx.x;
    const int r = ((rI & 3) << 10) + (rI >> 2);
    dst[rI] = b_ih[r] + b_hh[r];
}

// br2[o] = b_rr[o] + Wrr[o]·b_rp ; grid 2
__global__ void br2_k(float* __restrict__ br2, const float* __restrict__ Wrr,
                      const float* __restrict__ b_rp, const float* __restrict__ b_rr) {
    const int o = blockIdx.x * 256 + threadIdx.x;
    float s = b_rr[o];
    for (int m = 0; m < 512; m++) s += Wrr[o * 512 + m] * b_rp[m];
    br2[o] = s;
}

// biasGI[4u+g] = b_ih[r]+b_hh[r] + W_ih[r]·br2 ; grid 16
__global__ void biasg_k(float* __restrict__ dst, const float* __restrict__ Wih,
                        const float* __restrict__ b_ih, const float* __restrict__ b_hh,
                        const float* __restrict__ br2) {
    const int rI = blockIdx.x * 256 + threadIdx.x;
    const int r = ((rI & 3) << 10) + (rI >> 2);
    float s = b_ih[r] + b_hh[r];
    for (int o = 0; o < 512; o++) s += Wih[(size_t)r * 512 + o] * br2[o];
    dst[rI] = s;
}

// Acat2: cols 0..1023 = bf(x), cols 2048..3071 = bf(hx)
__global__ void init_sta(const float* __restrict__ x, const float* __restrict__ hx,
                         ushort_t* __restrict__ A2) {
    int idx = blockIdx.x * 256 + threadIdx.x;
    int b = idx >> 10, j = idx & 1023;
    A2[(size_t)b * 3072 + j] = f2bf(x[idx]);
    A2[(size_t)b * 3072 + 2048 + j] = f2bf(hx[idx]);
}

extern "C" void kernel_launch(void* const* d_in, const int* in_sizes, int n_in,
                              void* d_out, int out_size, void* d_ws, size_t ws_size,
                              hipStream_t stream) {
    const float* x        = (const float*)d_in[0];
    const float* hx       = (const float*)d_in[1];
    const float* cx       = (const float*)d_in[2];
    const float* W_ih_dec = (const float*)d_in[3];
    const float* W_hh_dec = (const float*)d_in[4];
    const float* b_ih_dec = (const float*)d_in[5];
    const float* b_hh_dec = (const float*)d_in[6];
    const float* W_r0     = (const float*)d_in[7];
    const float* b_r0     = (const float*)d_in[8];
    const float* W_rp     = (const float*)d_in[9];
    const float* b_rp     = (const float*)d_in[10];
    const float* W_rr     = (const float*)d_in[11];
    const float* b_rr     = (const float*)d_in[12];
    const float* W_s0     = (const float*)d_in[13];
    const float* b_s0     = (const float*)d_in[14];
    const float* W_ih_sta = (const float*)d_in[15];
    const float* W_hh_sta = (const float*)d_in[16];
    const float* b_ih_sta = (const float*)d_in[17];
    const float* b_hh_sta = (const float*)d_in[18];
    const float* W_sn     = (const float*)d_in[19];
    const float* b_sn     = (const float*)d_in[20];
    float* out = (float*)d_out;

    float* Act    = out;                          // [1024][512]
    float* ActBar = out + 524288;                 // [32][1024][512]
    float* Hx2    = out + 524288 + 16777216;      // [1024][1024]
    float* Cx2    = Hx2 + 1048576;                // [1024][1024]

    char* ws = (char*)d_ws;
    size_t off = 0;
    auto alloc = [&](size_t bytes) -> void* {
        void* p = ws + off;
        off += (bytes + 255) & ~(size_t)255;
        return p;
    };
    const size_t SLOT = 1048576;  // one [1024][1024] bf16 slab (elements)
    ushort_t* HDall  = (ushort_t*)alloc(33ull * SLOT * 2);   // hd0 + 32 hd's (69 MB)
    ushort_t* WgI    = (ushort_t*)alloc(4096ull * 1024 * 2); // folded loop weight
    ushort_t* WhhI   = (ushort_t*)alloc(4096ull * 1024 * 2); // s=0 weight (NOT aliased)
    ushort_t* WcatSI = (ushort_t*)alloc(4096ull * 3072 * 2); // static interleaved
    ushort_t* Wrpb   = (ushort_t*)alloc(512ull * 1024 * 2);
    ushort_t* Wr0b   = (ushort_t*)alloc(1024ull * 1024 * 2);
    ushort_t* Ws0b   = (ushort_t*)alloc(1024ull * 1024 * 2);
    ushort_t* Wsnb   = (ushort_t*)alloc(512ull * 1024 * 2);
    float*    biasDI = (float*)alloc(4096 * 4);
    float*    biasGI = (float*)alloc(4096 * 4);
    float*    biasSI = (float*)alloc(4096 * 4);
    float*    br2    = (float*)alloc(512 * 4);
    ushort_t* Acat2  = (ushort_t*)alloc(1024ull * 3072 * 2); // [x | xbar | hx]
    ushort_t* hbarb  = (ushort_t*)alloc(1024ull * 1024 * 2);
    ushort_t* hx2b   = (ushort_t*)alloc(1024ull * 1024 * 2);
    unsigned* barws  = (unsigned*)alloc(512 * 16 * 4);       // group/quarter flags
    if (ws_size < off) return;

    // Prep scratch aliased into HDall slots 1..12 — consumed before the decoder
    // loop overwrites the slot AND never re-read inside gates_rows (launch-
    // boundary invalidation clears any cached residue before it runs).
    float*    Wgf    = (float*)(HDall + 1 * SLOT);    // slots 1-8 (16 MB fp32)
    ushort_t* Wihb   = HDall + 9 * SLOT;              // slots 9-10
    ushort_t* WrpT   = HDall + 11 * SLOT;             // 1 MB
    ushort_t* Wrp2Tb = HDall + 11 * SLOT + 524288;    // 1 MB
    ushort_t* Wrrb   = HDall + 12 * SLOT;             // 0.5 MB

    // ---- packing & weight folding ----
    zero_bar<<<32, 256, 0, stream>>>(barws, 512 * 16);
    init_sta<<<4096, 256, 0, stream>>>(x, hx, Acat2);
    pack2_bf<<<dim3(2, 512), 256, 0, stream>>>(Wrrb, W_rr, 512, nullptr, 0);
    pack2_bf<<<dim3(2, 4096), 256, 0, stream>>>(Wihb, W_ih_dec, 512, nullptr, 0);
    pack2_bf<<<dim3(4, 512), 256, 0, stream>>>(Wrpb, W_rp, 1024, nullptr, 0);
    pack2_bf<<<dim3(4, 1024), 256, 0, stream>>>(Wr0b, W_r0, 1024, nullptr, 0);
    pack2_bf<<<dim3(4, 1024), 256, 0, stream>>>(Ws0b, W_s0, 1024, nullptr, 0);
    pack2_bf<<<dim3(4, 512), 256, 0, stream>>>(Wsnb, W_sn, 1024, nullptr, 0);
    tpose_bf<<<dim3(2, 1024), 256, 0, stream>>>(WrpT, W_rp, 512, 1024);
    ileave_whh_k<<<dim3(4, 4096), 256, 0, stream>>>(WhhI, W_hh_dec);
    bias_il_k<<<16, 256, 0, stream>>>(biasDI, b_ih_dec, b_hh_dec);
    ileave_sta_k<<<dim3(12, 4096), 256, 0, stream>>>(WcatSI, W_ih_sta, W_hh_sta);
    bias_il_k<<<16, 256, 0, stream>>>(biasSI, b_ih_sta, b_hh_sta);
    br2_k<<<2, 256, 0, stream>>>(br2, W_rr, b_rp, b_rr);
    biasg_k<<<16, 256, 0, stream>>>(biasGI, W_ih_dec, b_ih_dec, b_hh_dec, br2);

    // Wrp2T[k][o] = sum_m Wrp[m][k]*Wrr[o][m]  (M=1024,N=512,K=512)
    gemm_bt<false, true, false, false><<<dim3(4, 8, 1), 256, 0, stream>>>(
        WrpT, 512, Wrrb, 512, 512, 0, nullptr, nullptr, 0, 0, Wrp2Tb, 512);
    // Wgf[r][k] = sum_o W_ih[r][o]*Wrp2[o][k]  (M=4096,N=1024,K=512) fp32
    gemm_bt<true, false, false, false><<<dim3(8, 32, 1), 256, 0, stream>>>(
        Wihb, 512, Wrp2Tb, 512, 512, 0, nullptr, Wgf, 1024, 0, nullptr, 0);
    // WgI = interleave(Wgf + W_hh)
    ileave_add_k<<<dim3(4, 4096), 256, 0, stream>>>(WgI, Wgf, W_hh_dec);

    // hd0 = hx @ W_r0^T + b_r0 -> HDall slot 0 (bf16)
    gemm_bt<false, true, false, false><<<dim3(8, 8, 1), 256, 0, stream>>>(
        Acat2 + 2048, 3072, Wr0b, 1024, 1024, 0, b_r0, nullptr, 0, 0, HDall, 1024);

    // ---- decoder: all 32 steps, row-partitioned, per-span producer sync ----
    gates_rows<<<512, 512, 0, stream>>>(
        HDall, WhhI, WgI, biasDI, biasGI, cx, hbarb, barws);

    // ---- batched p: ActBar[s] = hd_{s+1} @ Wrp^T + b_rp  (M=32768,N=512,K=1024)
    gemm_bt<true, false, false, true><<<dim3(4, 256, 1), 256, 0, stream>>>(
        HDall + SLOT, 1024, Wrpb, 1024, 1024, 0, b_rp, ActBar, 512, 0, nullptr, 0);

    // xbar = relu(hbar @ W_s0^T + b_s0) -> Acat2 cols 1024..2047
    gemm_bt<false, true, true, false><<<dim3(8, 8, 1), 256, 0, stream>>>(
        hbarb, 1024, Ws0b, 1024, 1024, 0, b_s0, nullptr, 0, 0, Acat2 + 1024, 3072);

    // static LSTM fused (K=3072): -> Hx2 (fp32), Cx2 (fp32), hx2b (bf16)
    gates_fused<true, true><<<dim3(32, 16), 256, 0, stream>>>(
        Acat2, 3072, WcatSI, 3072, biasSI, cx, Cx2, hx2b, 1024, Hx2);

    // Act = hx2 @ W_sn^T + b_sn
    gemm_bt<true, false, false, true><<<dim3(4, 8, 1), 256, 0, stream>>>(
        hx2b, 1024, Wsnb, 1024, 1024, 0, b_sn, Act, 512, 0, nullptr, 0);

    (void)in_sizes; (void)n_in; (void)out_size;
}

// Round 9
// 1206.469 us; speedup vs baseline: 1.3743x; 1.3743x over previous
//
#include <hip/hip_runtime.h>
#include <hip/hip_bf16.h>
#include <stdint.h>

// B=1024, D_in=1024, D_hid=1024, D_out=512, D_future=32
// Outputs: Act [1024*512], Act_bar [32*1024*512], hx2 [1024*1024], cx2 [1024*1024]
//
// Algebraic restructure: r_t = hd_t@Wrp2^T + br2  (Wrp2 = Wrr@Wrp), so
//   gates_t = hd_{t-1} @ (W_ih@Wrp2 + W_hh)^T + (biasD + W_ih@br2)   [t>=1]
//   gates_0 = hd0 @ W_hh^T + biasD                                    [r0 = 0]
//
// R6: row-partitioned decoder, per-group flag sync (no global barrier).
// R7: hd published via relaxed agent atomics (no wbl2): 739us (23us/step).
// R8: REGRESSED (32-row tiles doubled B-traffic; span rotation broke L2
// A-sharing, FETCH 2x; per-span polls serialized). Fully reverted.
// R9: R7 + ONE change: publish via packed u64 atomics (4 bf16/store,
// 2 stores/thread) instead of 4x u32/thread -> 2x fewer coherence-point
// transactions (524K -> 262K per step). Publish path was the largest
// unaccounted per-step cost (~11us) in R7's budget.

typedef unsigned short ushort_t;
typedef unsigned long long u64_t;
typedef __attribute__((ext_vector_type(8))) short short8;   // 8 x bf16
typedef __attribute__((ext_vector_type(4))) float floatx4;  // 4 x fp32 acc

__device__ __forceinline__ unsigned short f2bf(float f) {
    unsigned int u = __float_as_uint(f);
    u += 0x7FFF + ((u >> 16) & 1);   // RNE
    return (unsigned short)(u >> 16);
}
__device__ __forceinline__ float bf2f(unsigned short u) {
    return __uint_as_float(((unsigned int)u) << 16);
}
__device__ __forceinline__ float sigm(float x) { return 1.f / (1.f + __expf(-x)); }

__device__ __forceinline__ void glds16(const ushort_t* g, const ushort_t* l) {
    __builtin_amdgcn_global_load_lds(
        (const __attribute__((address_space(1))) uint32_t*)g,
        (__attribute__((address_space(3))) uint32_t*)l, 16, 0, 0);
}

__device__ __forceinline__ unsigned ld_rlx(const unsigned* p) {
    return __hip_atomic_load(p, __ATOMIC_RELAXED, __HIP_MEMORY_SCOPE_AGENT);
}
__device__ __forceinline__ void st_rlx(unsigned* p, unsigned v) {
    __hip_atomic_store(p, v, __ATOMIC_RELAXED, __HIP_MEMORY_SCOPE_AGENT);
}
__device__ __forceinline__ void st_rlx64(u64_t* p, u64_t v) {
    __hip_atomic_store(p, v, __ATOMIC_RELAXED, __HIP_MEMORY_SCOPE_AGENT);
}

// ---------------- generic GEMM (round-2 proven, zero LDS conflicts) ----------
// C[m][n] = sum_k A[m][k]*Bw[n][k] (+bias[n]), optional relu; fp32/bf16 out.
// NT: nontemporal fp32 stores (pure outputs, avoid RFO). Grid (N/128, M/128, kz).
template <bool WF, bool WB, bool RELU, bool NT>
__global__ __launch_bounds__(256)
void gemm_bt(const ushort_t* __restrict__ A, int lda,
             const ushort_t* __restrict__ Bw, int ldb,
             int Kloop, int kzOff,
             const float* __restrict__ bias,
             float* __restrict__ Cf, int ldcf, size_t czStride,
             ushort_t* __restrict__ Cb, int ldcb) {
    __shared__ __align__(16) ushort_t As[128 * 32];
    __shared__ __align__(16) ushort_t Bs[128 * 32];
    const int t = threadIdx.x;
    const int l = t & 63;
    const int w = t >> 6;
    // XCD-aware bijective swizzle: XCD (flat%8) gets a contiguous m-range,
    // iterating n fastest -> A-panel + B-tile stay in the local L2.
    int bx = blockIdx.x, by = blockIdx.y;
    if ((gridDim.y & 7) == 0) {
        const int flat = bx + gridDim.x * by;
        const int xcd = flat & 7;
        const int j = flat >> 3;
        const int jm = j / gridDim.x;       // uniform per-block, cheap
        by = xcd * (gridDim.y >> 3) + jm;
        bx = j - jm * gridDim.x;
    }
    const int m0 = by << 7;
    const int n0 = bx << 7;
    const int kz = blockIdx.z;
    A  += (size_t)kz * kzOff;
    Bw += (size_t)kz * kzOff;
    if (WF) Cf += (size_t)kz * czStride;
    const int wm = (w >> 1) << 6;
    const int wn = (w & 1) << 6;
    const int lr = l & 15;
    const int lg = l >> 4;

    floatx4 acc[4][4] = {};

    const int srow = (w << 4) + (l >> 2);
    const int cc = ((l & 3) - ((l >> 3) & 3)) & 3;
    const int scol = cc << 3;
    const ushort_t* Ag0 = A + (size_t)(m0 + srow) * lda + scol;
    const ushort_t* Ag1 = A + (size_t)(m0 + 64 + srow) * lda + scol;
    const ushort_t* Bg0 = Bw + (size_t)(n0 + srow) * ldb + scol;
    const ushort_t* Bg1 = Bw + (size_t)(n0 + 64 + srow) * ldb + scol;
    const ushort_t* lA0 = &As[t * 8];
    const ushort_t* lA1 = &As[2048 + t * 8];
    const ushort_t* lB0 = &Bs[t * 8];
    const ushort_t* lB1 = &Bs[2048 + t * 8];

    int aoff[4], boff[4];
#pragma unroll
    for (int i = 0; i < 4; i++) {
        const int Ra = wm + i * 16 + lr;
        aoff[i] = ((Ra << 2) + ((lg + ((Ra >> 1) & 3)) & 3)) << 3;
        const int Rb = wn + i * 16 + lr;
        boff[i] = ((Rb << 2) + ((lg + ((Rb >> 1) & 3)) & 3)) << 3;
    }

    for (int kk = 0; kk < Kloop; kk += 32) {
        glds16(Ag0 + kk, lA0);
        glds16(Ag1 + kk, lA1);
        glds16(Bg0 + kk, lB0);
        glds16(Bg1 + kk, lB1);
        __syncthreads();
        short8 af[4], bfr[4];
#pragma unroll
        for (int i = 0; i < 4; i++) af[i] = *(const short8*)&As[aoff[i]];
#pragma unroll
        for (int j = 0; j < 4; j++) bfr[j] = *(const short8*)&Bs[boff[j]];
#pragma unroll
        for (int i = 0; i < 4; i++)
#pragma unroll
            for (int j = 0; j < 4; j++)
                acc[i][j] = __builtin_amdgcn_mfma_f32_16x16x32_bf16(af[i], bfr[j], acc[i][j], 0, 0, 0);
        __syncthreads();
    }

#pragma unroll
    for (int i = 0; i < 4; i++) {
#pragma unroll
        for (int j = 0; j < 4; j++) {
            const int col = n0 + wn + j * 16 + lr;
            const float bv = bias ? bias[col] : 0.f;
#pragma unroll
            for (int r = 0; r < 4; r++) {
                const int row = m0 + wm + i * 16 + lg * 4 + r;
                float v = acc[i][j][r] + bv;
                if (RELU) v = fmaxf(v, 0.f);
                if (WF) {
                    if (NT) __builtin_nontemporal_store(v, &Cf[(size_t)row * ldcf + col]);
                    else Cf[(size_t)row * ldcf + col] = v;
                }
                if (WB) Cb[(size_t)row * ldcb + col] = f2bf(v);
            }
        }
    }
}

// ---------------- fused gates GEMM + LSTM pointwise (single-step) -------------
// Still used for the static LSTM (K=3072). Same structure as before.
template <bool HF, bool NT>
__global__ __launch_bounds__(256, 2)
void gates_fused(const ushort_t* __restrict__ A, int lda,
                 const ushort_t* __restrict__ WI, int K,
                 const float* __restrict__ biasI,
                 const float* __restrict__ cin, float* __restrict__ cout,
                 ushort_t* __restrict__ hbf, int ldh,
                 float* __restrict__ hf) {
    __shared__ __align__(16) float Cs[64 * 132];         // 33.8 KB
    ushort_t* AsBase = (ushort_t*)Cs;                    // 2 bufs x 8192 elems = 32 KB
    const int t = threadIdx.x;
    const int l = t & 63;
    const int w = t >> 6;
    const int flat = blockIdx.x + (blockIdx.y << 5);
    const int xcd = flat & 7;
    const int jsw = flat >> 3;
    const int bn = (xcd << 2) + (jsw >> 4);   // 0..31 n-tile
    const int bm = jsw & 15;                  // 0..15 m-tile
    const int m0 = bm << 6;    // 64-row tile
    const int n0 = bn << 7;    // 128 gate-rows = 32 units
    const int u0 = bn << 5;
    const int lr = l & 15;
    const int lg = l >> 4;

    floatx4 acc[4][2] = {};

    const int srow = t >> 2;
    const int cc = ((t & 3) - ((t >> 3) & 3)) & 3;
    const int scol = cc << 3;
    const ushort_t* Ag = A + (size_t)(m0 + srow) * lda + scol;

    int aoff[4];
#pragma unroll
    for (int i = 0; i < 4; i++) {
        const int Ra = i * 16 + lr;
        aoff[i] = ((Ra << 2) + ((lg + ((Ra >> 1) & 3)) & 3)) << 3;
    }
    const ushort_t* BgW[2];
#pragma unroll
    for (int jf = 0; jf < 2; jf++)
        BgW[jf] = WI + (size_t)(n0 + (w << 5) + jf * 16 + lr) * K + (lg << 3);

    auto issueA = [&](int b, int sp) {
#pragma unroll
        for (int s = 0; s < 4; s++)
            glds16(Ag + sp * 128 + s * 32, AsBase + b * 8192 + s * 2048 + t * 8);
    };
    auto loadB = [&](short8 (&br)[4][2], int sp) {
#pragma unroll
        for (int s = 0; s < 4; s++)
#pragma unroll
            for (int jf = 0; jf < 2; jf++)
                br[s][jf] = *(const short8*)(BgW[jf] + sp * 128 + s * 32);
    };
    auto compute = [&](int b, short8 (&br)[4][2]) {
#pragma unroll
        for (int s = 0; s < 4; s++) {
            short8 af[4];
#pragma unroll
            for (int i = 0; i < 4; i++)
                af[i] = *(const short8*)(AsBase + b * 8192 + s * 2048 + aoff[i]);
#pragma unroll
            for (int i = 0; i < 4; i++)
#pragma unroll
                for (int jf = 0; jf < 2; jf++)
                    acc[i][jf] = __builtin_amdgcn_mfma_f32_16x16x32_bf16(af[i], br[s][jf], acc[i][jf], 0, 0, 0);
        }
    };

    short8 b0[4][2], b1[4][2];
    const int NS = K >> 7;
    issueA(0, 0);
    loadB(b0, 0);
    for (int sp = 0; sp < NS; sp += 2) {
        __syncthreads();
        if (sp + 1 < NS) { issueA(1, sp + 1); loadB(b1, sp + 1); }
        compute(0, b0);
        __syncthreads();
        if (sp + 2 < NS) { issueA(0, sp + 2); loadB(b0, sp + 2); }
        compute(1, b1);
    }
    __syncthreads();

#pragma unroll
    for (int i = 0; i < 4; i++)
#pragma unroll
        for (int jf = 0; jf < 2; jf++) {
            const int colb = (w << 5) + jf * 16 + lr;
#pragma unroll
            for (int r = 0; r < 4; r++)
                Cs[(i * 16 + lg * 4 + r) * 132 + colb] = acc[i][jf][r];
        }
    __syncthreads();

#pragma unroll
    for (int p = 0; p < 8; p++) {
        const int row = p * 8 + (t >> 5);
        const int uu = t & 31;
        const float4 g4 = *(const float4*)&Cs[row * 132 + uu * 4];
        const int grow = m0 + row;
        const int gu = u0 + uu;
        const float4 b4 = *(const float4*)&biasI[gu * 4];
        const float iv = sigm(g4.x + b4.x);
        const float fv = sigm(g4.y + b4.y);
        const float gv = tanhf(g4.z + b4.z);
        const float ov = sigm(g4.w + b4.w);
        const size_t cidx = (size_t)grow * 1024 + gu;
        const float c = fv * cin[cidx] + iv * gv;
        const float h = ov * tanhf(c);
        if (NT) __builtin_nontemporal_store(c, &cout[cidx]);
        else cout[cidx] = c;
        hbf[(size_t)grow * ldh + gu] = f2bf(h);
        if (HF) {
            if (NT) __builtin_nontemporal_store(h, &hf[cidx]);
            else hf[cidx] = h;
        }
    }
}

// ---------------- row-partitioned 32-step decoder (NO global barrier) ---------
// Grid 256 blocks x 512 threads (1 block/CU). Block (g = bid>>4, q = bid&15):
// rows [64g,64g+64) x gate-cols [256q,256q+256) (units [64q,64q+64)).
// XCD = bid%8 = q%8 -> 2 W-quarters = 1MB/XCD. Coarse sync: poll all 16
// group flags once per step (16 parallel relaxed pollers). hd published via
// packed-u64 relaxed agent atomics (4 bf16/store, 2 stores/thread).
__global__ __launch_bounds__(512, 1)
void gates_rows(ushort_t* __restrict__ HD,          // slot base; A(s) = HD + s*SLOT
                const ushort_t* __restrict__ Wh,    // WhhI   (s=0)
                const ushort_t* __restrict__ Wg,    // WgI    (s>=1)
                const float* __restrict__ biasD,
                const float* __restrict__ biasG,
                const float* __restrict__ cx,       // c init
                ushort_t* __restrict__ hbarb,
                unsigned* __restrict__ flags) {     // 256 x 16 u32 (64B apart)
    const size_t SLOT = 1048576;
    __shared__ __align__(16) float Cs[64 * 260];         // 66.6 KB
    ushort_t* AsBase = (ushort_t*)Cs;                    // 2 bufs x 8192 elems = 32 KB
    const int t = threadIdx.x;          // 0..511
    const int l = t & 63;
    const int w = t >> 6;               // 0..7 (wave); gate-cols [w*32,w*32+32)
    const int bid = blockIdx.x;
    const int g = bid >> 4;             // row group 0..15 (64 rows each)
    const int q = bid & 15;             // unit quarter 0..15 (64 units each)
    const int m0 = g << 6;              // 64 rows
    const int n0 = q << 8;              // 256 gate-cols
    const int u0 = q << 6;              // 64 units
    const int lr = l & 15;
    const int lg = l >> 4;
    const int fbase = g << 4;           // flag base for this group

    // A staging: 64 rows x 128k span, double-buffered. 512 threads stage
    // 4 subtiles (64r x 32k = 2048 elems each); threads [0,256) handle
    // subtiles 0-1, [256,512) handle 2-3.
    const int u8 = t & 255;
    const int pr = t >> 8;              // subtile-pair selector
    const int srow = u8 >> 2;
    const int cc = ((u8 & 3) - ((u8 >> 3) & 3)) & 3;
    const ushort_t* Ag = HD + (size_t)(m0 + srow) * 1024 + (cc << 3);  // slot 0

    int aoff[4];
#pragma unroll
    for (int i = 0; i < 4; i++) {
        const int Ra = i * 16 + lr;
        aoff[i] = ((Ra << 2) + ((lg + ((Ra >> 1) & 3)) & 3)) << 3;
    }

    // pointwise mapping: thread -> 4 adjacent units x 2 rows (rb, rb+32)
    const int v = t & 15;               // unit quad 0..15 (units u0+4v..u0+4v+3)
    const int rb = t >> 4;              // row 0..31 (also handles rb+32)
    const int gu0 = u0 + 4 * v;
    float4 bd[4], bg[4];
#pragma unroll
    for (int k = 0; k < 4; k++) {
        bd[k] = *(const float4*)&biasD[(gu0 + k) * 4];
        bg[k] = *(const float4*)&biasG[(gu0 + k) * 4];
    }
    float cst[2][4], hsum[2][4];
#pragma unroll
    for (int h = 0; h < 2; h++)
#pragma unroll
        for (int k = 0; k < 4; k++) {
            cst[h][k] = cx[(size_t)(m0 + rb + 32 * h) * 1024 + gu0 + k];
            hsum[h][k] = 0.f;
        }

    for (int s = 0; s < 32; ++s) {
        if (s) {
            // wait: all 16 quarters of group g have published slot s.
            // 16 parallel pollers (one line each), relaxed (no buffer_inv).
            if (t < 16)
                while (ld_rlx(&flags[(fbase | t) << 4]) < (unsigned)s)
                    __builtin_amdgcn_s_sleep(2);
            __syncthreads();
        }

        const ushort_t* W = s ? Wg : Wh;
        const ushort_t* BgW[2];
#pragma unroll
        for (int jf = 0; jf < 2; jf++)
            BgW[jf] = W + (size_t)(n0 + (w << 5) + jf * 16 + lr) * 1024 + (lg << 3);

        floatx4 acc[4][2] = {};

        auto issueA = [&](int b, int sp) {
#pragma unroll
            for (int j = 0; j < 2; j++) {
                const int ss = pr * 2 + j;
                glds16(Ag + sp * 128 + ss * 32,
                       AsBase + b * 8192 + ss * 2048 + u8 * 8);
            }
        };
        auto loadB = [&](short8 (&br)[4][2], int sp) {
#pragma unroll
            for (int ss = 0; ss < 4; ss++)
#pragma unroll
                for (int jf = 0; jf < 2; jf++)
                    br[ss][jf] = *(const short8*)(BgW[jf] + sp * 128 + ss * 32);
        };
        auto compute = [&](int b, short8 (&br)[4][2]) {
#pragma unroll
            for (int ss = 0; ss < 4; ss++) {
                short8 af[4];
#pragma unroll
                for (int i = 0; i < 4; i++)
                    af[i] = *(const short8*)(AsBase + b * 8192 + ss * 2048 + aoff[i]);
#pragma unroll
                for (int i = 0; i < 4; i++)
#pragma unroll
                    for (int jf = 0; jf < 2; jf++)
                        acc[i][jf] = __builtin_amdgcn_mfma_f32_16x16x32_bf16(af[i], br[ss][jf], acc[i][jf], 0, 0, 0);
            }
        };

        short8 b0[4][2], b1[4][2];
        issueA(0, 0);
        loadB(b0, 0);
        for (int sp = 0; sp < 8; sp += 2) {
            __syncthreads();              // drains span sp glds16
            if (sp + 1 < 8) { issueA(1, sp + 1); loadB(b1, sp + 1); }
            compute(0, b0);
            __syncthreads();              // drains span sp+1 glds16
            if (sp + 2 < 8) { issueA(0, sp + 2); loadB(b0, sp + 2); }
            compute(1, b1);
        }
        __syncthreads();                  // all ds_reads done before Cs overwrite

        // epilogue: acc -> Cs (stride 260, waves have disjoint col ranges)
#pragma unroll
        for (int i = 0; i < 4; i++)
#pragma unroll
            for (int jf = 0; jf < 2; jf++) {
                const int colb = (w << 5) + jf * 16 + lr;
#pragma unroll
                for (int r = 0; r < 4; r++)
                    Cs[(i * 16 + lg * 4 + r) * 260 + colb] = acc[i][jf][r];
            }
        __syncthreads();

        // pointwise: 4 units x 2 rows per thread; one packed u64 publish/row
        ushort_t* Hout = HD + (size_t)(s + 1) * SLOT;
#pragma unroll
        for (int h = 0; h < 2; h++) {
            const int row = rb + 32 * h;
            u64_t pack = 0;
#pragma unroll
            for (int k = 0; k < 4; k++) {
                const float4 g4 = *(const float4*)&Cs[row * 260 + v * 16 + 4 * k];
                const float4 b4 = s ? bg[k] : bd[k];
                const float iv = sigm(g4.x + b4.x);
                const float fv = sigm(g4.y + b4.y);
                const float gv = tanhf(g4.z + b4.z);
                const float ov = sigm(g4.w + b4.w);
                cst[h][k] = fv * cst[h][k] + iv * gv;
                const float hv = ov * tanhf(cst[h][k]);
                pack |= ((u64_t)f2bf(hv)) << (16 * k);
                hsum[h][k] += hv;
            }
            st_rlx64((u64_t*)&Hout[(size_t)(m0 + row) * 1024 + gu0], pack);
        }

        __syncthreads();                  // vmcnt(0): all publishes complete; Cs reads done
        if (s < 31 && t == 0)             // relaxed flag (no wbl2)
            st_rlx(&flags[(fbase | q) << 4], (unsigned)(s + 1));
        Ag += SLOT;                       // next step reads slot s+1
    }

    // hbar = mean over the 32 h's (fp32 accumulation, pre-rounding)
#pragma unroll
    for (int h = 0; h < 2; h++) {
        u64_t hb = 0;
#pragma unroll
        for (int k = 0; k < 4; k++)
            hb |= ((u64_t)f2bf(hsum[h][k] * (1.f / 32.f))) << (16 * k);
        *(u64_t*)&hbarb[(size_t)(m0 + rb + 32 * h) * 1024 + gu0] = hb;
    }
}

// ---------------- small prep kernels -----------------------------------------
__global__ void zero_bar(unsigned* __restrict__ b, int n) {
    int i = blockIdx.x * 256 + threadIdx.x;
    if (i < n) b[i] = 0u;
}

__global__ void pack2_bf(ushort_t* __restrict__ dst, const float* __restrict__ s1, int K1,
                         const float* __restrict__ s2, int K2) {
    const int n = blockIdx.y;
    const int k = blockIdx.x * 256 + threadIdx.x;
    const int Kt = K1 + K2;
    float v = (k < K1) ? s1[(size_t)n * K1 + k] : s2[(size_t)n * K2 + (k - K1)];
    dst[(size_t)n * Kt + k] = f2bf(v);
}

// dst[c][r] = bf(src[r][c]); grid (R/256, C)
__global__ void tpose_bf(ushort_t* __restrict__ dst, const float* __restrict__ src,
                         int R, int C) {
    const int c = blockIdx.y;
    const int r = blockIdx.x * 256 + threadIdx.x;
    dst[(size_t)c * R + r] = f2bf(src[(size_t)r * C + c]);
}

// WhhI[4u+g][k] = bf(Whh[(g<<10)+u][k]); grid (4, 4096)
__global__ void ileave_whh_k(ushort_t* __restrict__ dst, const float* __restrict__ Whh) {
    const int rI = blockIdx.y;
    const int k = blockIdx.x * 256 + threadIdx.x;
    const int r = ((rI & 3) << 10) + (rI >> 2);
    dst[(size_t)rI * 1024 + k] = f2bf(Whh[(size_t)r * 1024 + k]);
}

// WgI[4u+g][k] = bf(Wgf[r][k] + Whh[r][k]); grid (4, 4096)
__global__ void ileave_add_k(ushort_t* __restrict__ dst, const float* __restrict__ Wgf,
                             const float* __restrict__ Whh) {
    const int rI = blockIdx.y;
    const int k = blockIdx.x * 256 + threadIdx.x;
    const int r = ((rI & 3) << 10) + (rI >> 2);
    dst[(size_t)rI * 1024 + k] = f2bf(Wgf[(size_t)r * 1024 + k] + Whh[(size_t)r * 1024 + k]);
}

// WcatSI[4u+g][k]: k<2048 from Wih_sta[r][k], else Whh_sta[r][k-2048]; grid (12, 4096)
__global__ void ileave_sta_k(ushort_t* __restrict__ dst, const float* __restrict__ Wih,
                             const float* __restrict__ Whh) {
    const int rI = blockIdx.y;
    const int k = blockIdx.x * 256 + threadIdx.x;
    const int r = ((rI & 3) << 10) + (rI >> 2);
    float v = (k < 2048) ? Wih[(size_t)r * 2048 + k] : Whh[(size_t)r * 1024 + (k - 2048)];
    dst[(size_t)rI * 3072 + k] = f2bf(v);
}

// biasI[4u+g] = b_ih[r] + b_hh[r]; grid 16
__global__ void bias_il_k(float* __restrict__ dst, const float* __restrict__ b_ih,
                          const float* __restrict__ b_hh) {
    const int rI = blockIdx.x * 256 + threadIdx.x;
    const int r = ((rI & 3) << 10) + (rI >> 2);
    dst[rI] = b_ih[r] + b_hh[r];
}

// br2[o] = b_rr[o] + Wrr[o]·b_rp ; grid 2
__global__ void br2_k(float* __restrict__ br2, const float* __restrict__ Wrr,
                      const float* __restrict__ b_rp, const float* __restrict__ b_rr) {
    const int o = blockIdx.x * 256 + threadIdx.x;
    float s = b_rr[o];
    for (int m = 0; m < 512; m++) s += Wrr[o * 512 + m] * b_rp[m];
    br2[o] = s;
}

// biasGI[4u+g] = b_ih[r]+b_hh[r] + W_ih[r]·br2 ; grid 16
__global__ void biasg_k(float* __restrict__ dst, const float* __restrict__ Wih,
                        const float* __restrict__ b_ih, const float* __restrict__ b_hh,
                        const float* __restrict__ br2) {
    const int rI = blockIdx.x * 256 + threadIdx.x;
    const int r = ((rI & 3) << 10) + (rI >> 2);
    float s = b_ih[r] + b_hh[r];
    for (int o = 0; o < 512; o++) s += Wih[(size_t)r * 512 + o] * br2[o];
    dst[rI] = s;
}

// Acat2: cols 0..1023 = bf(x), cols 2048..3071 = bf(hx)
__global__ void init_sta(const float* __restrict__ x, const float* __restrict__ hx,
                         ushort_t* __restrict__ A2) {
    int idx = blockIdx.x * 256 + threadIdx.x;
    int b = idx >> 10, j = idx & 1023;
    A2[(size_t)b * 3072 + j] = f2bf(x[idx]);
    A2[(size_t)b * 3072 + 2048 + j] = f2bf(hx[idx]);
}

extern "C" void kernel_launch(void* const* d_in, const int* in_sizes, int n_in,
                              void* d_out, int out_size, void* d_ws, size_t ws_size,
                              hipStream_t stream) {
    const float* x        = (const float*)d_in[0];
    const float* hx       = (const float*)d_in[1];
    const float* cx       = (const float*)d_in[2];
    const float* W_ih_dec = (const float*)d_in[3];
    const float* W_hh_dec = (const float*)d_in[4];
    const float* b_ih_dec = (const float*)d_in[5];
    const float* b_hh_dec = (const float*)d_in[6];
    const float* W_r0     = (const float*)d_in[7];
    const float* b_r0     = (const float*)d_in[8];
    const float* W_rp     = (const float*)d_in[9];
    const float* b_rp     = (const float*)d_in[10];
    const float* W_rr     = (const float*)d_in[11];
    const float* b_rr     = (const float*)d_in[12];
    const float* W_s0     = (const float*)d_in[13];
    const float* b_s0     = (const float*)d_in[14];
    const float* W_ih_sta = (const float*)d_in[15];
    const float* W_hh_sta = (const float*)d_in[16];
    const float* b_ih_sta = (const float*)d_in[17];
    const float* b_hh_sta = (const float*)d_in[18];
    const float* W_sn     = (const float*)d_in[19];
    const float* b_sn     = (const float*)d_in[20];
    float* out = (float*)d_out;

    float* Act    = out;                          // [1024][512]
    float* ActBar = out + 524288;                 // [32][1024][512]
    float* Hx2    = out + 524288 + 16777216;      // [1024][1024]
    float* Cx2    = Hx2 + 1048576;                // [1024][1024]

    char* ws = (char*)d_ws;
    size_t off = 0;
    auto alloc = [&](size_t bytes) -> void* {
        void* p = ws + off;
        off += (bytes + 255) & ~(size_t)255;
        return p;
    };
    const size_t SLOT = 1048576;  // one [1024][1024] bf16 slab (elements)
    ushort_t* HDall  = (ushort_t*)alloc(33ull * SLOT * 2);   // hd0 + 32 hd's (69 MB)
    ushort_t* WgI    = (ushort_t*)alloc(4096ull * 1024 * 2); // folded loop weight
    ushort_t* WhhI   = (ushort_t*)alloc(4096ull * 1024 * 2); // s=0 weight (NOT aliased)
    ushort_t* WcatSI = (ushort_t*)alloc(4096ull * 3072 * 2); // static interleaved
    ushort_t* Wrpb   = (ushort_t*)alloc(512ull * 1024 * 2);
    ushort_t* Wr0b   = (ushort_t*)alloc(1024ull * 1024 * 2);
    ushort_t* Ws0b   = (ushort_t*)alloc(1024ull * 1024 * 2);
    ushort_t* Wsnb   = (ushort_t*)alloc(512ull * 1024 * 2);
    float*    biasDI = (float*)alloc(4096 * 4);
    float*    biasGI = (float*)alloc(4096 * 4);
    float*    biasSI = (float*)alloc(4096 * 4);
    float*    br2    = (float*)alloc(512 * 4);
    ushort_t* Acat2  = (ushort_t*)alloc(1024ull * 3072 * 2); // [x | xbar | hx]
    ushort_t* hbarb  = (ushort_t*)alloc(1024ull * 1024 * 2);
    ushort_t* hx2b   = (ushort_t*)alloc(1024ull * 1024 * 2);
    unsigned* barws  = (unsigned*)alloc(256 * 16 * 4);       // group/quarter flags
    if (ws_size < off) return;

    // Prep scratch aliased into HDall slots 1..12 — consumed before the decoder
    // loop overwrites the slot AND never re-read inside gates_rows (launch-
    // boundary invalidation clears any cached residue before it runs).
    float*    Wgf    = (float*)(HDall + 1 * SLOT);    // slots 1-8 (16 MB fp32)
    ushort_t* Wihb   = HDall + 9 * SLOT;              // slots 9-10
    ushort_t* WrpT   = HDall + 11 * SLOT;             // 1 MB
    ushort_t* Wrp2Tb = HDall + 11 * SLOT + 524288;    // 1 MB
    ushort_t* Wrrb   = HDall + 12 * SLOT;             // 0.5 MB

    // ---- packing & weight folding ----
    zero_bar<<<16, 256, 0, stream>>>(barws, 256 * 16);
    init_sta<<<4096, 256, 0, stream>>>(x, hx, Acat2);
    pack2_bf<<<dim3(2, 512), 256, 0, stream>>>(Wrrb, W_rr, 512, nullptr, 0);
    pack2_bf<<<dim3(2, 4096), 256, 0, stream>>>(Wihb, W_ih_dec, 512, nullptr, 0);
    pack2_bf<<<dim3(4, 512), 256, 0, stream>>>(Wrpb, W_rp, 1024, nullptr, 0);
    pack2_bf<<<dim3(4, 1024), 256, 0, stream>>>(Wr0b, W_r0, 1024, nullptr, 0);
    pack2_bf<<<dim3(4, 1024), 256, 0, stream>>>(Ws0b, W_s0, 1024, nullptr, 0);
    pack2_bf<<<dim3(4, 512), 256, 0, stream>>>(Wsnb, W_sn, 1024, nullptr, 0);
    tpose_bf<<<dim3(2, 1024), 256, 0, stream>>>(WrpT, W_rp, 512, 1024);
    ileave_whh_k<<<dim3(4, 4096), 256, 0, stream>>>(WhhI, W_hh_dec);
    bias_il_k<<<16, 256, 0, stream>>>(biasDI, b_ih_dec, b_hh_dec);
    ileave_sta_k<<<dim3(12, 4096), 256, 0, stream>>>(WcatSI, W_ih_sta, W_hh_sta);
    bias_il_k<<<16, 256, 0, stream>>>(biasSI, b_ih_sta, b_hh_sta);
    br2_k<<<2, 256, 0, stream>>>(br2, W_rr, b_rp, b_rr);
    biasg_k<<<16, 256, 0, stream>>>(biasGI, W_ih_dec, b_ih_dec, b_hh_dec, br2);

    // Wrp2T[k][o] = sum_m Wrp[m][k]*Wrr[o][m]  (M=1024,N=512,K=512)
    gemm_bt<false, true, false, false><<<dim3(4, 8, 1), 256, 0, stream>>>(
        WrpT, 512, Wrrb, 512, 512, 0, nullptr, nullptr, 0, 0, Wrp2Tb, 512);
    // Wgf[r][k] = sum_o W_ih[r][o]*Wrp2[o][k]  (M=4096,N=1024,K=512) fp32
    gemm_bt<true, false, false, false><<<dim3(8, 32, 1), 256, 0, stream>>>(
        Wihb, 512, Wrp2Tb, 512, 512, 0, nullptr, Wgf, 1024, 0, nullptr, 0);
    // WgI = interleave(Wgf + W_hh)
    ileave_add_k<<<dim3(4, 4096), 256, 0, stream>>>(WgI, Wgf, W_hh_dec);

    // hd0 = hx @ W_r0^T + b_r0 -> HDall slot 0 (bf16)
    gemm_bt<false, true, false, false><<<dim3(8, 8, 1), 256, 0, stream>>>(
        Acat2 + 2048, 3072, Wr0b, 1024, 1024, 0, b_r0, nullptr, 0, 0, HDall, 1024);

    // ---- decoder: all 32 steps, row-partitioned, per-group flag sync ----
    gates_rows<<<256, 512, 0, stream>>>(
        HDall, WhhI, WgI, biasDI, biasGI, cx, hbarb, barws);

    // ---- batched p: ActBar[s] = hd_{s+1} @ Wrp^T + b_rp  (M=32768,N=512,K=1024)
    gemm_bt<true, false, false, true><<<dim3(4, 256, 1), 256, 0, stream>>>(
        HDall + SLOT, 1024, Wrpb, 1024, 1024, 0, b_rp, ActBar, 512, 0, nullptr, 0);

    // xbar = relu(hbar @ W_s0^T + b_s0) -> Acat2 cols 1024..2047
    gemm_bt<false, true, true, false><<<dim3(8, 8, 1), 256, 0, stream>>>(
        hbarb, 1024, Ws0b, 1024, 1024, 0, b_s0, nullptr, 0, 0, Acat2 + 1024, 3072);

    // static LSTM fused (K=3072): -> Hx2 (fp32), Cx2 (fp32), hx2b (bf16)
    gates_fused<true, true><<<dim3(32, 16), 256, 0, stream>>>(
        Acat2, 3072, WcatSI, 3072, biasSI, cx, Cx2, hx2b, 1024, Hx2);

    // Act = hx2 @ W_sn^T + b_sn
    gemm_bt<true, false, false, true><<<dim3(4, 8, 1), 256, 0, stream>>>(
        hx2b, 1024, Wsnb, 1024, 1024, 0, b_sn, Act, 512, 0, nullptr, 0);

    (void)in_sizes; (void)n_in; (void)out_size;
}

// Round 10
// 1131.041 us; speedup vs baseline: 1.4659x; 1.0667x over previous
//
#include <hip/hip_runtime.h>
#include <hip/hip_bf16.h>
#include <stdint.h>

// B=1024, D_in=1024, D_hid=1024, D_out=512, D_future=32
// Outputs: Act [1024*512], Act_bar [32*1024*512], hx2 [1024*1024], cx2 [1024*1024]
//
// Algebraic restructure: r_t = hd_t@Wrp2^T + br2  (Wrp2 = Wrr@Wrp), so
//   gates_t = hd_{t-1} @ (W_ih@Wrp2 + W_hh)^T + (biasD + W_ih@br2)   [t>=1]
//   gates_0 = hd0 @ W_hh^T + biasD                                    [r0 = 0]
//
// R7: row-partitioned decoder, relaxed-atomic publish: 739us (23us/step);
//     MfmaUtil 15% = exact MFMA floor -> ~20us/step is stall.
// R9:  u64 publish: NULL -> publish transaction count is not the cost.
// R8:  2 blocks/CU via M-split REGRESSED (B-traffic doubled; counter-attributed).
// R10: 2 blocks/CU via N-SPLIT (keeps M=64 -> B-reuse intact). 512 blocks x
// 256 thr, __launch_bounds__(256,2): block (g in 16 groups x 64 rows,
// q in 32 quarters x 32 units). K-loop geometry identical to the proven
// gates_fused (64r x 128 gate-cols, 4 waves). q = xcd + 8*qi -> 4 W-slices
// = 1MB/XCD (unchanged). Two co-resident blocks at independent phases:
// one computes while the other sits in flag-wait / publish-drain.

typedef unsigned short ushort_t;
typedef unsigned long long u64_t;
typedef __attribute__((ext_vector_type(8))) short short8;   // 8 x bf16
typedef __attribute__((ext_vector_type(4))) float floatx4;  // 4 x fp32 acc

__device__ __forceinline__ unsigned short f2bf(float f) {
    unsigned int u = __float_as_uint(f);
    u += 0x7FFF + ((u >> 16) & 1);   // RNE
    return (unsigned short)(u >> 16);
}
__device__ __forceinline__ float bf2f(unsigned short u) {
    return __uint_as_float(((unsigned int)u) << 16);
}
__device__ __forceinline__ float sigm(float x) { return 1.f / (1.f + __expf(-x)); }

__device__ __forceinline__ void glds16(const ushort_t* g, const ushort_t* l) {
    __builtin_amdgcn_global_load_lds(
        (const __attribute__((address_space(1))) uint32_t*)g,
        (__attribute__((address_space(3))) uint32_t*)l, 16, 0, 0);
}

__device__ __forceinline__ unsigned ld_rlx(const unsigned* p) {
    return __hip_atomic_load(p, __ATOMIC_RELAXED, __HIP_MEMORY_SCOPE_AGENT);
}
__device__ __forceinline__ void st_rlx(unsigned* p, unsigned v) {
    __hip_atomic_store(p, v, __ATOMIC_RELAXED, __HIP_MEMORY_SCOPE_AGENT);
}
__device__ __forceinline__ void st_rlx64(u64_t* p, u64_t v) {
    __hip_atomic_store(p, v, __ATOMIC_RELAXED, __HIP_MEMORY_SCOPE_AGENT);
}

// ---------------- generic GEMM (round-2 proven, zero LDS conflicts) ----------
// C[m][n] = sum_k A[m][k]*Bw[n][k] (+bias[n]), optional relu; fp32/bf16 out.
// NT: nontemporal fp32 stores (pure outputs, avoid RFO). Grid (N/128, M/128, kz).
template <bool WF, bool WB, bool RELU, bool NT>
__global__ __launch_bounds__(256)
void gemm_bt(const ushort_t* __restrict__ A, int lda,
             const ushort_t* __restrict__ Bw, int ldb,
             int Kloop, int kzOff,
             const float* __restrict__ bias,
             float* __restrict__ Cf, int ldcf, size_t czStride,
             ushort_t* __restrict__ Cb, int ldcb) {
    __shared__ __align__(16) ushort_t As[128 * 32];
    __shared__ __align__(16) ushort_t Bs[128 * 32];
    const int t = threadIdx.x;
    const int l = t & 63;
    const int w = t >> 6;
    // XCD-aware bijective swizzle: XCD (flat%8) gets a contiguous m-range,
    // iterating n fastest -> A-panel + B-tile stay in the local L2.
    int bx = blockIdx.x, by = blockIdx.y;
    if ((gridDim.y & 7) == 0) {
        const int flat = bx + gridDim.x * by;
        const int xcd = flat & 7;
        const int j = flat >> 3;
        const int jm = j / gridDim.x;       // uniform per-block, cheap
        by = xcd * (gridDim.y >> 3) + jm;
        bx = j - jm * gridDim.x;
    }
    const int m0 = by << 7;
    const int n0 = bx << 7;
    const int kz = blockIdx.z;
    A  += (size_t)kz * kzOff;
    Bw += (size_t)kz * kzOff;
    if (WF) Cf += (size_t)kz * czStride;
    const int wm = (w >> 1) << 6;
    const int wn = (w & 1) << 6;
    const int lr = l & 15;
    const int lg = l >> 4;

    floatx4 acc[4][4] = {};

    const int srow = (w << 4) + (l >> 2);
    const int cc = ((l & 3) - ((l >> 3) & 3)) & 3;
    const int scol = cc << 3;
    const ushort_t* Ag0 = A + (size_t)(m0 + srow) * lda + scol;
    const ushort_t* Ag1 = A + (size_t)(m0 + 64 + srow) * lda + scol;
    const ushort_t* Bg0 = Bw + (size_t)(n0 + srow) * ldb + scol;
    const ushort_t* Bg1 = Bw + (size_t)(n0 + 64 + srow) * ldb + scol;
    const ushort_t* lA0 = &As[t * 8];
    const ushort_t* lA1 = &As[2048 + t * 8];
    const ushort_t* lB0 = &Bs[t * 8];
    const ushort_t* lB1 = &Bs[2048 + t * 8];

    int aoff[4], boff[4];
#pragma unroll
    for (int i = 0; i < 4; i++) {
        const int Ra = wm + i * 16 + lr;
        aoff[i] = ((Ra << 2) + ((lg + ((Ra >> 1) & 3)) & 3)) << 3;
        const int Rb = wn + i * 16 + lr;
        boff[i] = ((Rb << 2) + ((lg + ((Rb >> 1) & 3)) & 3)) << 3;
    }

    for (int kk = 0; kk < Kloop; kk += 32) {
        glds16(Ag0 + kk, lA0);
        glds16(Ag1 + kk, lA1);
        glds16(Bg0 + kk, lB0);
        glds16(Bg1 + kk, lB1);
        __syncthreads();
        short8 af[4], bfr[4];
#pragma unroll
        for (int i = 0; i < 4; i++) af[i] = *(const short8*)&As[aoff[i]];
#pragma unroll
        for (int j = 0; j < 4; j++) bfr[j] = *(const short8*)&Bs[boff[j]];
#pragma unroll
        for (int i = 0; i < 4; i++)
#pragma unroll
            for (int j = 0; j < 4; j++)
                acc[i][j] = __builtin_amdgcn_mfma_f32_16x16x32_bf16(af[i], bfr[j], acc[i][j], 0, 0, 0);
        __syncthreads();
    }

#pragma unroll
    for (int i = 0; i < 4; i++) {
#pragma unroll
        for (int j = 0; j < 4; j++) {
            const int col = n0 + wn + j * 16 + lr;
            const float bv = bias ? bias[col] : 0.f;
#pragma unroll
            for (int r = 0; r < 4; r++) {
                const int row = m0 + wm + i * 16 + lg * 4 + r;
                float v = acc[i][j][r] + bv;
                if (RELU) v = fmaxf(v, 0.f);
                if (WF) {
                    if (NT) __builtin_nontemporal_store(v, &Cf[(size_t)row * ldcf + col]);
                    else Cf[(size_t)row * ldcf + col] = v;
                }
                if (WB) Cb[(size_t)row * ldcb + col] = f2bf(v);
            }
        }
    }
}

// ---------------- fused gates GEMM + LSTM pointwise (single-step) -------------
// Still used for the static LSTM (K=3072). Same structure as before.
template <bool HF, bool NT>
__global__ __launch_bounds__(256, 2)
void gates_fused(const ushort_t* __restrict__ A, int lda,
                 const ushort_t* __restrict__ WI, int K,
                 const float* __restrict__ biasI,
                 const float* __restrict__ cin, float* __restrict__ cout,
                 ushort_t* __restrict__ hbf, int ldh,
                 float* __restrict__ hf) {
    __shared__ __align__(16) float Cs[64 * 132];         // 33.8 KB
    ushort_t* AsBase = (ushort_t*)Cs;                    // 2 bufs x 8192 elems = 32 KB
    const int t = threadIdx.x;
    const int l = t & 63;
    const int w = t >> 6;
    const int flat = blockIdx.x + (blockIdx.y << 5);
    const int xcd = flat & 7;
    const int jsw = flat >> 3;
    const int bn = (xcd << 2) + (jsw >> 4);   // 0..31 n-tile
    const int bm = jsw & 15;                  // 0..15 m-tile
    const int m0 = bm << 6;    // 64-row tile
    const int n0 = bn << 7;    // 128 gate-rows = 32 units
    const int u0 = bn << 5;
    const int lr = l & 15;
    const int lg = l >> 4;

    floatx4 acc[4][2] = {};

    const int srow = t >> 2;
    const int cc = ((t & 3) - ((t >> 3) & 3)) & 3;
    const int scol = cc << 3;
    const ushort_t* Ag = A + (size_t)(m0 + srow) * lda + scol;

    int aoff[4];
#pragma unroll
    for (int i = 0; i < 4; i++) {
        const int Ra = i * 16 + lr;
        aoff[i] = ((Ra << 2) + ((lg + ((Ra >> 1) & 3)) & 3)) << 3;
    }
    const ushort_t* BgW[2];
#pragma unroll
    for (int jf = 0; jf < 2; jf++)
        BgW[jf] = WI + (size_t)(n0 + (w << 5) + jf * 16 + lr) * K + (lg << 3);

    auto issueA = [&](int b, int sp) {
#pragma unroll
        for (int s = 0; s < 4; s++)
            glds16(Ag + sp * 128 + s * 32, AsBase + b * 8192 + s * 2048 + t * 8);
    };
    auto loadB = [&](short8 (&br)[4][2], int sp) {
#pragma unroll
        for (int s = 0; s < 4; s++)
#pragma unroll
            for (int jf = 0; jf < 2; jf++)
                br[s][jf] = *(const short8*)(BgW[jf] + sp * 128 + s * 32);
    };
    auto compute = [&](int b, short8 (&br)[4][2]) {
#pragma unroll
        for (int s = 0; s < 4; s++) {
            short8 af[4];
#pragma unroll
            for (int i = 0; i < 4; i++)
                af[i] = *(const short8*)(AsBase + b * 8192 + s * 2048 + aoff[i]);
#pragma unroll
            for (int i = 0; i < 4; i++)
#pragma unroll
                for (int jf = 0; jf < 2; jf++)
                    acc[i][jf] = __builtin_amdgcn_mfma_f32_16x16x32_bf16(af[i], br[s][jf], acc[i][jf], 0, 0, 0);
        }
    };

    short8 b0[4][2], b1[4][2];
    const int NS = K >> 7;
    issueA(0, 0);
    loadB(b0, 0);
    for (int sp = 0; sp < NS; sp += 2) {
        __syncthreads();
        if (sp + 1 < NS) { issueA(1, sp + 1); loadB(b1, sp + 1); }
        compute(0, b0);
        __syncthreads();
        if (sp + 2 < NS) { issueA(0, sp + 2); loadB(b0, sp + 2); }
        compute(1, b1);
    }
    __syncthreads();

#pragma unroll
    for (int i = 0; i < 4; i++)
#pragma unroll
        for (int jf = 0; jf < 2; jf++) {
            const int colb = (w << 5) + jf * 16 + lr;
#pragma unroll
            for (int r = 0; r < 4; r++)
                Cs[(i * 16 + lg * 4 + r) * 132 + colb] = acc[i][jf][r];
        }
    __syncthreads();

#pragma unroll
    for (int p = 0; p < 8; p++) {
        const int row = p * 8 + (t >> 5);
        const int uu = t & 31;
        const float4 g4 = *(const float4*)&Cs[row * 132 + uu * 4];
        const int grow = m0 + row;
        const int gu = u0 + uu;
        const float4 b4 = *(const float4*)&biasI[gu * 4];
        const float iv = sigm(g4.x + b4.x);
        const float fv = sigm(g4.y + b4.y);
        const float gv = tanhf(g4.z + b4.z);
        const float ov = sigm(g4.w + b4.w);
        const size_t cidx = (size_t)grow * 1024 + gu;
        const float c = fv * cin[cidx] + iv * gv;
        const float h = ov * tanhf(c);
        if (NT) __builtin_nontemporal_store(c, &cout[cidx]);
        else cout[cidx] = c;
        hbf[(size_t)grow * ldh + gu] = f2bf(h);
        if (HF) {
            if (NT) __builtin_nontemporal_store(h, &hf[cidx]);
            else hf[cidx] = h;
        }
    }
}

// ---------------- row-partitioned 32-step decoder (N-split, 2 blocks/CU) ------
// Grid 512 blocks x 256 threads, __launch_bounds__(256,2) -> all co-resident.
// Block (g = 0..15, q = 0..31): rows [64g,64g+64) x gate-cols [128q,128q+128)
// (units [32q,32q+32)). bid = xcd + 8*(g + 16*qi), q = xcd + 8*qi -> each XCD
// reads 4 W-slices = 1MB (L2-resident); M=64 keeps B-reuse (R8 lesson).
// hd published via packed-u64 relaxed agent atomics; flag per (g,q) relaxed
// after __syncthreads (vmcnt(0) -> data complete at coherence point first).
__global__ __launch_bounds__(256, 2)
void gates_rows(ushort_t* __restrict__ HD,          // slot base; A(s) = HD + s*SLOT
                const ushort_t* __restrict__ Wh,    // WhhI   (s=0)
                const ushort_t* __restrict__ Wg,    // WgI    (s>=1)
                const float* __restrict__ biasD,
                const float* __restrict__ biasG,
                const float* __restrict__ cx,       // c init
                ushort_t* __restrict__ hbarb,
                unsigned* __restrict__ flags) {     // 512 x 16 u32 (64B apart)
    const size_t SLOT = 1048576;
    __shared__ __align__(16) float Cs[64 * 132];         // 33.8 KB
    ushort_t* AsBase = (ushort_t*)Cs;                    // 2 bufs x 8192 elems = 32 KB
    const int t = threadIdx.x;          // 0..255
    const int l = t & 63;
    const int w = t >> 6;               // 0..3 (wave); gate-cols [32w,32w+32)
    const int bid = blockIdx.x;
    const int xcd = bid & 7;
    const int j = bid >> 3;             // 0..63
    const int g = j & 15;               // row group 0..15 (64 rows each)
    const int q = xcd + ((j >> 4) << 3);// unit slice 0..31 (32 units each)
    const int m0 = g << 6;              // 64 rows
    const int n0 = q << 7;              // 128 gate-cols
    const int u0 = q << 5;              // 32 units
    const int lr = l & 15;
    const int lg = l >> 4;
    const int fbase = g << 5;           // flag base for this group (32 slices)

    // A staging: identical to gates_fused (64 rows x 128k span, dbuf).
    const int srow = t >> 2;
    const int cc = ((t & 3) - ((t >> 3) & 3)) & 3;
    const ushort_t* Ag = HD + (size_t)(m0 + srow) * 1024 + (cc << 3);  // slot 0

    int aoff[4];
#pragma unroll
    for (int i = 0; i < 4; i++) {
        const int Ra = i * 16 + lr;
        aoff[i] = ((Ra << 2) + ((lg + ((Ra >> 1) & 3)) & 3)) << 3;
    }

    // pointwise mapping: thread -> 4 adjacent units x 2 rows (rb, rb+32)
    const int v = t & 7;                // unit quad 0..7 (units u0+4v..u0+4v+3)
    const int rb = t >> 3;              // row 0..31 (also handles rb+32)
    const int gu0 = u0 + 4 * v;
    float4 bd[4], bg[4];
#pragma unroll
    for (int k = 0; k < 4; k++) {
        bd[k] = *(const float4*)&biasD[(gu0 + k) * 4];
        bg[k] = *(const float4*)&biasG[(gu0 + k) * 4];
    }
    float cst[2][4], hsum[2][4];
#pragma unroll
    for (int h = 0; h < 2; h++)
#pragma unroll
        for (int k = 0; k < 4; k++) {
            cst[h][k] = cx[(size_t)(m0 + rb + 32 * h) * 1024 + gu0 + k];
            hsum[h][k] = 0.f;
        }

    for (int s = 0; s < 32; ++s) {
        if (s) {
            // wait: all 32 slices of group g have published slot s.
            // 32 parallel pollers (one line each), relaxed (no buffer_inv).
            if (t < 32)
                while (ld_rlx(&flags[(fbase | t) << 4]) < (unsigned)s)
                    __builtin_amdgcn_s_sleep(2);
            __syncthreads();
        }

        const ushort_t* W = s ? Wg : Wh;
        const ushort_t* BgW[2];
#pragma unroll
        for (int jf = 0; jf < 2; jf++)
            BgW[jf] = W + (size_t)(n0 + (w << 5) + jf * 16 + lr) * 1024 + (lg << 3);

        floatx4 acc[4][2] = {};

        auto issueA = [&](int b, int sp) {
#pragma unroll
            for (int ss = 0; ss < 4; ss++)
                glds16(Ag + sp * 128 + ss * 32, AsBase + b * 8192 + ss * 2048 + t * 8);
        };
        auto loadB = [&](short8 (&br)[4][2], int sp) {
#pragma unroll
            for (int ss = 0; ss < 4; ss++)
#pragma unroll
                for (int jf = 0; jf < 2; jf++)
                    br[ss][jf] = *(const short8*)(BgW[jf] + sp * 128 + ss * 32);
        };
        auto compute = [&](int b, short8 (&br)[4][2]) {
#pragma unroll
            for (int ss = 0; ss < 4; ss++) {
                short8 af[4];
#pragma unroll
                for (int i = 0; i < 4; i++)
                    af[i] = *(const short8*)(AsBase + b * 8192 + ss * 2048 + aoff[i]);
#pragma unroll
                for (int i = 0; i < 4; i++)
#pragma unroll
                    for (int jf = 0; jf < 2; jf++)
                        acc[i][jf] = __builtin_amdgcn_mfma_f32_16x16x32_bf16(af[i], br[ss][jf], acc[i][jf], 0, 0, 0);
            }
        };

        short8 b0[4][2], b1[4][2];
        issueA(0, 0);
        loadB(b0, 0);
        for (int sp = 0; sp < 8; sp += 2) {
            __syncthreads();              // drains span sp glds16
            if (sp + 1 < 8) { issueA(1, sp + 1); loadB(b1, sp + 1); }
            compute(0, b0);
            __syncthreads();              // drains span sp+1 glds16
            if (sp + 2 < 8) { issueA(0, sp + 2); loadB(b0, sp + 2); }
            compute(1, b1);
        }
        __syncthreads();                  // all ds_reads done before Cs overwrite

        // epilogue: acc -> Cs (stride 132, waves have disjoint col ranges)
#pragma unroll
        for (int i = 0; i < 4; i++)
#pragma unroll
            for (int jf = 0; jf < 2; jf++) {
                const int colb = (w << 5) + jf * 16 + lr;
#pragma unroll
                for (int r = 0; r < 4; r++)
                    Cs[(i * 16 + lg * 4 + r) * 132 + colb] = acc[i][jf][r];
            }
        __syncthreads();

        // pointwise: 4 units x 2 rows per thread; one packed u64 publish/row
        ushort_t* Hout = HD + (size_t)(s + 1) * SLOT;
#pragma unroll
        for (int h = 0; h < 2; h++) {
            const int row = rb + 32 * h;
            u64_t pack = 0;
#pragma unroll
            for (int k = 0; k < 4; k++) {
                const float4 g4 = *(const float4*)&Cs[row * 132 + v * 16 + 4 * k];
                const float4 b4 = s ? bg[k] : bd[k];
                const float iv = sigm(g4.x + b4.x);
                const float fv = sigm(g4.y + b4.y);
                const float gv = tanhf(g4.z + b4.z);
                const float ov = sigm(g4.w + b4.w);
                cst[h][k] = fv * cst[h][k] + iv * gv;
                const float hv = ov * tanhf(cst[h][k]);
                pack |= ((u64_t)f2bf(hv)) << (16 * k);
                hsum[h][k] += hv;
            }
            u64_t* dst = (u64_t*)&Hout[(size_t)(m0 + row) * 1024 + gu0];
            if (s < 31) st_rlx64(dst, pack);  // write-through publish
            else *dst = pack;                 // last slot: kernel-end release flushes
        }

        __syncthreads();                  // vmcnt(0): all publishes complete; Cs reads done
        if (s < 31 && t == 0)             // relaxed flag (no wbl2)
            st_rlx(&flags[(fbase | q) << 4], (unsigned)(s + 1));
        Ag += SLOT;                       // next step reads slot s+1
    }

    // hbar = mean over the 32 h's (fp32 accumulation, pre-rounding)
#pragma unroll
    for (int h = 0; h < 2; h++) {
        u64_t hb = 0;
#pragma unroll
        for (int k = 0; k < 4; k++)
            hb |= ((u64_t)f2bf(hsum[h][k] * (1.f / 32.f))) << (16 * k);
        *(u64_t*)&hbarb[(size_t)(m0 + rb + 32 * h) * 1024 + gu0] = hb;
    }
}

// ---------------- small prep kernels -----------------------------------------
__global__ void zero_bar(unsigned* __restrict__ b, int n) {
    int i = blockIdx.x * 256 + threadIdx.x;
    if (i < n) b[i] = 0u;
}

__global__ void pack2_bf(ushort_t* __restrict__ dst, const float* __restrict__ s1, int K1,
                         const float* __restrict__ s2, int K2) {
    const int n = blockIdx.y;
    const int k = blockIdx.x * 256 + threadIdx.x;
    const int Kt = K1 + K2;
    float v = (k < K1) ? s1[(size_t)n * K1 + k] : s2[(size_t)n * K2 + (k - K1)];
    dst[(size_t)n * Kt + k] = f2bf(v);
}

// dst[c][r] = bf(src[r][c]); grid (R/256, C)
__global__ void tpose_bf(ushort_t* __restrict__ dst, const float* __restrict__ src,
                         int R, int C) {
    const int c = blockIdx.y;
    const int r = blockIdx.x * 256 + threadIdx.x;
    dst[(size_t)c * R + r] = f2bf(src[(size_t)r * C + c]);
}

// WhhI[4u+g][k] = bf(Whh[(g<<10)+u][k]); grid (4, 4096)
__global__ void ileave_whh_k(ushort_t* __restrict__ dst, const float* __restrict__ Whh) {
    const int rI = blockIdx.y;
    const int k = blockIdx.x * 256 + threadIdx.x;
    const int r = ((rI & 3) << 10) + (rI >> 2);
    dst[(size_t)rI * 1024 + k] = f2bf(Whh[(size_t)r * 1024 + k]);
}

// WgI[4u+g][k] = bf(Wgf[r][k] + Whh[r][k]); grid (4, 4096)
__global__ void ileave_add_k(ushort_t* __restrict__ dst, const float* __restrict__ Wgf,
                             const float* __restrict__ Whh) {
    const int rI = blockIdx.y;
    const int k = blockIdx.x * 256 + threadIdx.x;
    const int r = ((rI & 3) << 10) + (rI >> 2);
    dst[(size_t)rI * 1024 + k] = f2bf(Wgf[(size_t)r * 1024 + k] + Whh[(size_t)r * 1024 + k]);
}

// WcatSI[4u+g][k]: k<2048 from Wih_sta[r][k], else Whh_sta[r][k-2048]; grid (12, 4096)
__global__ void ileave_sta_k(ushort_t* __restrict__ dst, const float* __restrict__ Wih,
                             const float* __restrict__ Whh) {
    const int rI = blockIdx.y;
    const int k = blockIdx.x * 256 + threadIdx.x;
    const int r = ((rI & 3) << 10) + (rI >> 2);
    float v = (k < 2048) ? Wih[(size_t)r * 2048 + k] : Whh[(size_t)r * 1024 + (k - 2048)];
    dst[(size_t)rI * 3072 + k] = f2bf(v);
}

// biasI[4u+g] = b_ih[r] + b_hh[r]; grid 16
__global__ void bias_il_k(float* __restrict__ dst, const float* __restrict__ b_ih,
                          const float* __restrict__ b_hh) {
    const int rI = blockIdx.x * 256 + threadIdx.x;
    const int r = ((rI & 3) << 10) + (rI >> 2);
    dst[rI] = b_ih[r] + b_hh[r];
}

// br2[o] = b_rr[o] + Wrr[o]·b_rp ; grid 2
__global__ void br2_k(float* __restrict__ br2, const float* __restrict__ Wrr,
                      const float* __restrict__ b_rp, const float* __restrict__ b_rr) {
    const int o = blockIdx.x * 256 + threadIdx.x;
    float s = b_rr[o];
    for (int m = 0; m < 512; m++) s += Wrr[o * 512 + m] * b_rp[m];
    br2[o] = s;
}

// biasGI[4u+g] = b_ih[r]+b_hh[r] + W_ih[r]·br2 ; grid 16
__global__ void biasg_k(float* __restrict__ dst, const float* __restrict__ Wih,
                        const float* __restrict__ b_ih, const float* __restrict__ b_hh,
                        const float* __restrict__ br2) {
    const int rI = blockIdx.x * 256 + threadIdx.x;
    const int r = ((rI & 3) << 10) + (rI >> 2);
    float s = b_ih[r] + b_hh[r];
    for (int o = 0; o < 512; o++) s += Wih[(size_t)r * 512 + o] * br2[o];
    dst[rI] = s;
}

// Acat2: cols 0..1023 = bf(x), cols 2048..3071 = bf(hx)
__global__ void init_sta(const float* __restrict__ x, const float* __restrict__ hx,
                         ushort_t* __restrict__ A2) {
    int idx = blockIdx.x * 256 + threadIdx.x;
    int b = idx >> 10, j = idx & 1023;
    A2[(size_t)b * 3072 + j] = f2bf(x[idx]);
    A2[(size_t)b * 3072 + 2048 + j] = f2bf(hx[idx]);
}

extern "C" void kernel_launch(void* const* d_in, const int* in_sizes, int n_in,
                              void* d_out, int out_size, void* d_ws, size_t ws_size,
                              hipStream_t stream) {
    const float* x        = (const float*)d_in[0];
    const float* hx       = (const float*)d_in[1];
    const float* cx       = (const float*)d_in[2];
    const float* W_ih_dec = (const float*)d_in[3];
    const float* W_hh_dec = (const float*)d_in[4];
    const float* b_ih_dec = (const float*)d_in[5];
    const float* b_hh_dec = (const float*)d_in[6];
    const float* W_r0     = (const float*)d_in[7];
    const float* b_r0     = (const float*)d_in[8];
    const float* W_rp     = (const float*)d_in[9];
    const float* b_rp     = (const float*)d_in[10];
    const float* W_rr     = (const float*)d_in[11];
    const float* b_rr     = (const float*)d_in[12];
    const float* W_s0     = (const float*)d_in[13];
    const float* b_s0     = (const float*)d_in[14];
    const float* W_ih_sta = (const float*)d_in[15];
    const float* W_hh_sta = (const float*)d_in[16];
    const float* b_ih_sta = (const float*)d_in[17];
    const float* b_hh_sta = (const float*)d_in[18];
    const float* W_sn     = (const float*)d_in[19];
    const float* b_sn     = (const float*)d_in[20];
    float* out = (float*)d_out;

    float* Act    = out;                          // [1024][512]
    float* ActBar = out + 524288;                 // [32][1024][512]
    float* Hx2    = out + 524288 + 16777216;      // [1024][1024]
    float* Cx2    = Hx2 + 1048576;                // [1024][1024]

    char* ws = (char*)d_ws;
    size_t off = 0;
    auto alloc = [&](size_t bytes) -> void* {
        void* p = ws + off;
        off += (bytes + 255) & ~(size_t)255;
        return p;
    };
    const size_t SLOT = 1048576;  // one [1024][1024] bf16 slab (elements)
    ushort_t* HDall  = (ushort_t*)alloc(33ull * SLOT * 2);   // hd0 + 32 hd's (69 MB)
    ushort_t* WgI    = (ushort_t*)alloc(4096ull * 1024 * 2); // folded loop weight
    ushort_t* WhhI   = (ushort_t*)alloc(4096ull * 1024 * 2); // s=0 weight (NOT aliased)
    ushort_t* WcatSI = (ushort_t*)alloc(4096ull * 3072 * 2); // static interleaved
    ushort_t* Wrpb   = (ushort_t*)alloc(512ull * 1024 * 2);
    ushort_t* Wr0b   = (ushort_t*)alloc(1024ull * 1024 * 2);
    ushort_t* Ws0b   = (ushort_t*)alloc(1024ull * 1024 * 2);
    ushort_t* Wsnb   = (ushort_t*)alloc(512ull * 1024 * 2);
    float*    biasDI = (float*)alloc(4096 * 4);
    float*    biasGI = (float*)alloc(4096 * 4);
    float*    biasSI = (float*)alloc(4096 * 4);
    float*    br2    = (float*)alloc(512 * 4);
    ushort_t* Acat2  = (ushort_t*)alloc(1024ull * 3072 * 2); // [x | xbar | hx]
    ushort_t* hbarb  = (ushort_t*)alloc(1024ull * 1024 * 2);
    ushort_t* hx2b   = (ushort_t*)alloc(1024ull * 1024 * 2);
    unsigned* barws  = (unsigned*)alloc(512 * 16 * 4);       // (g,q) flags
    if (ws_size < off) return;

    // Prep scratch aliased into HDall slots 1..12 — consumed before the decoder
    // loop overwrites the slot AND never re-read inside gates_rows (launch-
    // boundary invalidation clears any cached residue before it runs).
    float*    Wgf    = (float*)(HDall + 1 * SLOT);    // slots 1-8 (16 MB fp32)
    ushort_t* Wihb   = HDall + 9 * SLOT;              // slots 9-10
    ushort_t* WrpT   = HDall + 11 * SLOT;             // 1 MB
    ushort_t* Wrp2Tb = HDall + 11 * SLOT + 524288;    // 1 MB
    ushort_t* Wrrb   = HDall + 12 * SLOT;             // 0.5 MB

    // ---- packing & weight folding ----
    zero_bar<<<32, 256, 0, stream>>>(barws, 512 * 16);
    init_sta<<<4096, 256, 0, stream>>>(x, hx, Acat2);
    pack2_bf<<<dim3(2, 512), 256, 0, stream>>>(Wrrb, W_rr, 512, nullptr, 0);
    pack2_bf<<<dim3(2, 4096), 256, 0, stream>>>(Wihb, W_ih_dec, 512, nullptr, 0);
    pack2_bf<<<dim3(4, 512), 256, 0, stream>>>(Wrpb, W_rp, 1024, nullptr, 0);
    pack2_bf<<<dim3(4, 1024), 256, 0, stream>>>(Wr0b, W_r0, 1024, nullptr, 0);
    pack2_bf<<<dim3(4, 1024), 256, 0, stream>>>(Ws0b, W_s0, 1024, nullptr, 0);
    pack2_bf<<<dim3(4, 512), 256, 0, stream>>>(Wsnb, W_sn, 1024, nullptr, 0);
    tpose_bf<<<dim3(2, 1024), 256, 0, stream>>>(WrpT, W_rp, 512, 1024);
    ileave_whh_k<<<dim3(4, 4096), 256, 0, stream>>>(WhhI, W_hh_dec);
    bias_il_k<<<16, 256, 0, stream>>>(biasDI, b_ih_dec, b_hh_dec);
    ileave_sta_k<<<dim3(12, 4096), 256, 0, stream>>>(WcatSI, W_ih_sta, W_hh_sta);
    bias_il_k<<<16, 256, 0, stream>>>(biasSI, b_ih_sta, b_hh_sta);
    br2_k<<<2, 256, 0, stream>>>(br2, W_rr, b_rp, b_rr);
    biasg_k<<<16, 256, 0, stream>>>(biasGI, W_ih_dec, b_ih_dec, b_hh_dec, br2);

    // Wrp2T[k][o] = sum_m Wrp[m][k]*Wrr[o][m]  (M=1024,N=512,K=512)
    gemm_bt<false, true, false, false><<<dim3(4, 8, 1), 256, 0, stream>>>(
        WrpT, 512, Wrrb, 512, 512, 0, nullptr, nullptr, 0, 0, Wrp2Tb, 512);
    // Wgf[r][k] = sum_o W_ih[r][o]*Wrp2[o][k]  (M=4096,N=1024,K=512) fp32
    gemm_bt<true, false, false, false><<<dim3(8, 32, 1), 256, 0, stream>>>(
        Wihb, 512, Wrp2Tb, 512, 512, 0, nullptr, Wgf, 1024, 0, nullptr, 0);
    // WgI = interleave(Wgf + W_hh)
    ileave_add_k<<<dim3(4, 4096), 256, 0, stream>>>(WgI, Wgf, W_hh_dec);

    // hd0 = hx @ W_r0^T + b_r0 -> HDall slot 0 (bf16)
    gemm_bt<false, true, false, false><<<dim3(8, 8, 1), 256, 0, stream>>>(
        Acat2 + 2048, 3072, Wr0b, 1024, 1024, 0, b_r0, nullptr, 0, 0, HDall, 1024);

    // ---- decoder: all 32 steps, row-partitioned, per-group flag sync ----
    gates_rows<<<512, 256, 0, stream>>>(
        HDall, WhhI, WgI, biasDI, biasGI, cx, hbarb, barws);

    // ---- batched p: ActBar[s] = hd_{s+1} @ Wrp^T + b_rp  (M=32768,N=512,K=1024)
    gemm_bt<true, false, false, true><<<dim3(4, 256, 1), 256, 0, stream>>>(
        HDall + SLOT, 1024, Wrpb, 1024, 1024, 0, b_rp, ActBar, 512, 0, nullptr, 0);

    // xbar = relu(hbar @ W_s0^T + b_s0) -> Acat2 cols 1024..2047
    gemm_bt<false, true, true, false><<<dim3(8, 8, 1), 256, 0, stream>>>(
        hbarb, 1024, Ws0b, 1024, 1024, 0, b_s0, nullptr, 0, 0, Acat2 + 1024, 3072);

    // static LSTM fused (K=3072): -> Hx2 (fp32), Cx2 (fp32), hx2b (bf16)
    gates_fused<true, true><<<dim3(32, 16), 256, 0, stream>>>(
        Acat2, 3072, WcatSI, 3072, biasSI, cx, Cx2, hx2b, 1024, Hx2);

    // Act = hx2 @ W_sn^T + b_sn
    gemm_bt<true, false, false, true><<<dim3(4, 8, 1), 256, 0, stream>>>(
        hx2b, 1024, Wsnb, 1024, 1024, 0, b_sn, Act, 512, 0, nullptr, 0);

    (void)in_sizes; (void)n_in; (void)out_size;
}